// Round 1
// baseline (791.705 us; speedup 1.0000x reference)
//
#include <hip/hip_runtime.h>
#include <hip/hip_bf16.h>
#include <math.h>

// Problem dims (fixed by reference setup_inputs)
constexpr int Nn = 50000;  // nodes
constexpr int Ee = 10000;  // edges
constexpr int Ll = 50;     // seq len
constexpr int LuU = 20;    // user seq len
constexpr int Dd = 128;    // hidden dim
constexpr int Bb = 512;    // batch
constexpr int TVv = 768;   // text-vector dim
constexpr int Dw = 130;    // D+2
constexpr int BL = Bb * Ll; // 25600 rows in attention tensors

// ---------------- block reduction (blockDim.x == 256) ----------------
__device__ __forceinline__ float block_sum_256(float v, volatile float* scr) {
#pragma unroll
  for (int o = 32; o > 0; o >>= 1) v += __shfl_down(v, o, 64);
  __syncthreads();                      // protect scr from previous use
  if ((threadIdx.x & 63) == 0) scr[threadIdx.x >> 6] = v;
  __syncthreads();
  return scr[0] + scr[1] + scr[2] + scr[3];
}

// ---------------- HGNN: cosine / inter_nw ----------------
__global__ __launch_bounds__(256) void k_cos(const float* __restrict__ w3,
                                             float* __restrict__ dotb,
                                             float* __restrict__ nrmb) {
  __shared__ float scr[4];
  int i = blockIdx.x;
  const float* row = w3 + (size_t)i * TVv;
  float d = 0.f, n = 0.f;
  for (int j = threadIdx.x; j < TVv; j += 256) {
    float a = row[j];
    d += a * w3[j];   // tv = w3[0]
    n += a * a;
  }
  d = block_sum_256(d, scr);
  n = block_sum_256(n, scr);
  if (threadIdx.x == 0) { dotb[i] = d; nrmb[i] = n; }
}

__global__ __launch_bounds__(256) void k_internw(const float* __restrict__ dotb,
                                                 const float* __restrict__ nrmb,
                                                 float* __restrict__ internw) {
  __shared__ float scr[4];
  float n0 = sqrtf(nrmb[0]);
  float s = 0.f;
  for (int i = threadIdx.x; i < TVv; i += 256)
    s += dotb[i] / (n0 * sqrtf(nrmb[i]));
  s = block_sum_256(s, scr);
  if (threadIdx.x == 0) *internw = s / (float)TVv;
}

// ---------------- generic 128-wide row GEMM: out[r][j] = scale * sum_k in[r][k] * w[k][j]
// MODE 0: in-row = in0[r] + in1[gidx[r]], scale = *scalep   (compute x)
// MODE 1: in-row = in0[r], scale = 1                         (e1, q, k, v)
template <int MODE>
__global__ __launch_bounds__(256) void k_mm128(const float* __restrict__ in0,
                                               const float* __restrict__ in1,
                                               const int* __restrict__ gidx,
                                               const float* __restrict__ w,
                                               const float* __restrict__ scalep,
                                               float* __restrict__ out, int nrows) {
  __shared__ float wl[Dd * Dd];   // 64 KB
  __shared__ float il[32][Dd];    // 16 KB
  for (int i = threadIdx.x; i < Dd * Dd; i += 256) wl[i] = w[i];
  float scale = 1.f;
  if constexpr (MODE == 0) scale = *scalep;
  int nch = (nrows + 31) >> 5;
  for (int ch = blockIdx.x; ch < nch; ch += gridDim.x) {
    int r0 = ch << 5;
    __syncthreads();  // previous chunk's readers done; also covers wl on first iter
    for (int e = threadIdx.x; e < 32 * Dd; e += 256) {
      int rr = e >> 7, k = e & 127;
      int r = r0 + rr;
      float v = 0.f;
      if (r < nrows) {
        if constexpr (MODE == 0)
          v = in0[(size_t)r * Dd + k] + in1[(size_t)gidx[r] * Dd + k];
        else
          v = in0[(size_t)r * Dd + k];
      }
      il[rr][k] = v;
    }
    __syncthreads();
    int rr0 = (threadIdx.x >> 5) << 2;   // 4 rows per thread
    int j0 = (threadIdx.x & 31) << 2;    // 4 cols per thread
    float4 acc[4];
#pragma unroll
    for (int i = 0; i < 4; i++) acc[i] = make_float4(0.f, 0.f, 0.f, 0.f);
#pragma unroll 8
    for (int k = 0; k < Dd; k += 4) {
      float4 a[4], ww[4];
#pragma unroll
      for (int i = 0; i < 4; i++) a[i] = *(const float4*)&il[rr0 + i][k];
#pragma unroll
      for (int kk = 0; kk < 4; kk++) ww[kk] = *(const float4*)&wl[(k + kk) * Dd + j0];
#pragma unroll
      for (int i = 0; i < 4; i++) {
        float av[4] = {a[i].x, a[i].y, a[i].z, a[i].w};
#pragma unroll
        for (int kk = 0; kk < 4; kk++) {
          acc[i].x += av[kk] * ww[kk].x;
          acc[i].y += av[kk] * ww[kk].y;
          acc[i].z += av[kk] * ww[kk].z;
          acc[i].w += av[kk] * ww[kk].w;
        }
      }
    }
#pragma unroll
    for (int i = 0; i < 4; i++) {
      int r = r0 + rr0 + i;
      if (r < nrows) {
        float4 o = acc[i];
        o.x *= scale; o.y *= scale; o.z *= scale; o.w *= scale;
        *(float4*)&out[(size_t)r * Dd + j0] = o;
      }
    }
  }
}

// ---------------- gather + norm-weighted reduce (edge/node) ----------------
// out[r] = (cnt>0) ? mean over nonpad l of src[idx[r,l]] : src[0]   (+optional relu)
template <bool RELU>
__global__ __launch_bounds__(128) void k_gather(const float* __restrict__ src,
                                                const int* __restrict__ idx, int L,
                                                float* __restrict__ out) {
  int r = blockIdx.x, c = threadIdx.x;
  const int* row = idx + (size_t)r * L;
  float acc = 0.f; int cnt = 0;
  for (int l = 0; l < L; l++) {
    int id = row[l];
    if (id > 0) { acc += src[(size_t)id * Dd + c]; cnt++; }
  }
  float v = cnt ? acc / (float)cnt : src[c];  // cnt==0 => all ids 0 => mean = src[0]
  if (RELU) v = fmaxf(v, 0.f);
  out[(size_t)r * Dd + c] = v;
}

// ---------------- build attention inputs ----------------
__global__ __launch_bounds__(128) void k_hidden(const float* __restrict__ node,
                                                const int* __restrict__ data_idx,
                                                const int* __restrict__ seq,
                                                const int* __restrict__ tsmp,
                                                const int* __restrict__ uinf,
                                                const int* __restrict__ ulev,
                                                const float* __restrict__ time_emb,
                                                const float* __restrict__ inf_emb,
                                                const float* __restrict__ pos_emb,
                                                float* __restrict__ hidT,
                                                float* __restrict__ hidS) {
  int bl = blockIdx.x;
  int b = bl / Ll, l = bl % Ll;
  int c = threadIdx.x;
  int e = data_idx[b];
  int sid = seq[(size_t)e * Ll + l];
  float base = node[(size_t)sid * Dd + c];
  size_t o = (size_t)bl * Dd + c;
  hidT[o] = base + time_emb[(size_t)tsmp[(size_t)e * Ll + l] * Dd + c];
  hidS[o] = base + inf_emb[(size_t)uinf[(size_t)e * Ll + l] * Dd + c]
                 + pos_emb[(size_t)ulev[(size_t)e * Ll + l] * Dd + c];
}

// ---------------- per-(b,h) attention: scores -> softmax -> PV ----------------
__global__ __launch_bounds__(64) void k_attn(const float* __restrict__ q,
                                             const float* __restrict__ k,
                                             const float* __restrict__ v,
                                             const int* __restrict__ data_idx,
                                             const int* __restrict__ seq,
                                             float* __restrict__ ctx) {
  int b = blockIdx.x >> 3, h = blockIdx.x & 7;
  __shared__ float Kl[Ll][16], Vl[Ll][16];
  __shared__ int maskl[Ll];
  int e = data_idx[b];
  for (int i = threadIdx.x; i < Ll; i += 64)
    maskl[i] = (seq[(size_t)e * Ll + i] == 0);
  for (int i = threadIdx.x; i < Ll * 16; i += 64) {
    int l = i >> 4, d = i & 15;
    size_t o = ((size_t)(b * Ll + l)) * Dd + h * 16 + d;
    Kl[l][d] = k[o];
    Vl[l][d] = v[o];
  }
  __syncthreads();
  int qi = threadIdx.x;
  if (qi < Ll) {
    size_t qo = ((size_t)(b * Ll + qi)) * Dd + h * 16;
    float qv[16];
#pragma unroll
    for (int d = 0; d < 16; d++) qv[d] = q[qo + d];
    float sc[Ll];
    float m = -1e30f;
#pragma unroll
    for (int ki = 0; ki < Ll; ki++) {
      float s;
      if (maskl[ki]) s = -1e9f;
      else {
        s = 0.f;
#pragma unroll
        for (int d = 0; d < 16; d++) s += qv[d] * Kl[ki][d];
        s *= 0.25f;  // 1/sqrt(16)
      }
      sc[ki] = s;
      m = fmaxf(m, s);
    }
    float sum = 0.f;
#pragma unroll
    for (int ki = 0; ki < Ll; ki++) { float p = expf(sc[ki] - m); sc[ki] = p; sum += p; }
    float inv = 1.f / sum;
    float o[16];
#pragma unroll
    for (int d = 0; d < 16; d++) o[d] = 0.f;
#pragma unroll
    for (int ki = 0; ki < Ll; ki++) {
      float p = sc[ki];
#pragma unroll
      for (int d = 0; d < 16; d++) o[d] += p * Vl[ki][d];
    }
#pragma unroll
    for (int d = 0; d < 16; d++) ctx[qo + d] = o[d] * inv;
  }
}

// ---------------- out = LayerNorm(ctx @ wo + hid) * g + b ----------------
// rows (=25600) must be a multiple of 32 (full lanes needed for shfl LN reduce)
__global__ __launch_bounds__(256) void k_projln(const float* __restrict__ ctx,
                                                const float* __restrict__ hid,
                                                const float* __restrict__ wo,
                                                const float* __restrict__ g,
                                                const float* __restrict__ bta,
                                                float* __restrict__ out, int nrows) {
  __shared__ float wl[Dd * Dd];
  __shared__ float il[32][Dd];
  for (int i = threadIdx.x; i < Dd * Dd; i += 256) wl[i] = wo[i];
  int nch = (nrows + 31) >> 5;
  for (int ch = blockIdx.x; ch < nch; ch += gridDim.x) {
    int r0 = ch << 5;
    __syncthreads();
    for (int e = threadIdx.x; e < 32 * Dd; e += 256) {
      int rr = e >> 7, k = e & 127;
      il[rr][k] = ctx[(size_t)(r0 + rr) * Dd + k];
    }
    __syncthreads();
    int rr0 = (threadIdx.x >> 5) << 2;
    int j0 = (threadIdx.x & 31) << 2;
    float4 acc[4];
#pragma unroll
    for (int i = 0; i < 4; i++) acc[i] = make_float4(0.f, 0.f, 0.f, 0.f);
#pragma unroll 8
    for (int k = 0; k < Dd; k += 4) {
      float4 a[4], ww[4];
#pragma unroll
      for (int i = 0; i < 4; i++) a[i] = *(const float4*)&il[rr0 + i][k];
#pragma unroll
      for (int kk = 0; kk < 4; kk++) ww[kk] = *(const float4*)&wl[(k + kk) * Dd + j0];
#pragma unroll
      for (int i = 0; i < 4; i++) {
        float av[4] = {a[i].x, a[i].y, a[i].z, a[i].w};
#pragma unroll
        for (int kk = 0; kk < 4; kk++) {
          acc[i].x += av[kk] * ww[kk].x;
          acc[i].y += av[kk] * ww[kk].y;
          acc[i].z += av[kk] * ww[kk].z;
          acc[i].w += av[kk] * ww[kk].w;
        }
      }
    }
#pragma unroll
    for (int i = 0; i < 4; i++) {
      int r = r0 + rr0 + i;
      float4 t = acc[i];
      float4 hres = *(const float4*)&hid[(size_t)r * Dd + j0];
      t.x += hres.x; t.y += hres.y; t.z += hres.z; t.w += hres.w;
      float s1 = t.x + t.y + t.z + t.w;
      float s2 = t.x * t.x + t.y * t.y + t.z * t.z + t.w * t.w;
#pragma unroll
      for (int o = 16; o > 0; o >>= 1) {  // reduce across the 32 lanes holding this row
        s1 += __shfl_xor(s1, o, 64);
        s2 += __shfl_xor(s2, o, 64);
      }
      float mu = s1 * (1.f / Dd);
      float var = s2 * (1.f / Dd) - mu * mu;
      float rs = rsqrtf(var + 1e-6f);
      float4 oo;
      oo.x = (t.x - mu) * rs * g[j0 + 0] + bta[j0 + 0];
      oo.y = (t.y - mu) * rs * g[j0 + 1] + bta[j0 + 1];
      oo.z = (t.z - mu) * rs * g[j0 + 2] + bta[j0 + 2];
      oo.w = (t.w - mu) * rs * g[j0 + 3] + bta[j0 + 3];
      *(float4*)&out[(size_t)r * Dd + j0] = oo;
    }
  }
}

// ---------------- news = (nor_b-weighted sum of att) ++ extras, then @ W ----------------
// BR 0: extras = spread[e][2:4]/86400 ; BR 1: extras = spread[e][0:2]
template <int BR>
__global__ __launch_bounds__(256) void k_news(const float* __restrict__ att,
                                              const int* __restrict__ data_idx,
                                              const int* __restrict__ seq,
                                              const float* __restrict__ spread,
                                              const float* __restrict__ W,
                                              float* __restrict__ out) {
  __shared__ float row[Dw];
  int b = blockIdx.x;
  int e = data_idx[b];
  const int* sb = seq + (size_t)e * Ll;
  int cnt = 0;
  for (int l = 0; l < Ll; l++) cnt += (sb[l] > 0);
  int c = threadIdx.x;
  if (c < Dd) {
    float acc = 0.f;
    if (cnt > 0) {
      for (int l = 0; l < Ll; l++)
        if (sb[l] > 0) acc += att[((size_t)b * Ll + l) * Dd + c];
      acc /= (float)cnt;
    } else {
      for (int l = 0; l < Ll; l++) acc += att[((size_t)b * Ll + l) * Dd + c];
      acc *= (1.f / (float)Ll);
    }
    row[c] = acc;
  } else if (c < Dw) {
    int cc = c - Dd;
    row[c] = (BR == 0) ? spread[(size_t)e * 4 + 2 + cc] * (1.f / 86400.f)
                       : spread[(size_t)e * 4 + cc];
  }
  __syncthreads();
  if (c < Dw) {
    float acc = 0.f;
    for (int kk = 0; kk < Dw; kk++) acc += row[kk] * W[(size_t)kk * Dw + c];
    out[(size_t)b * Dw + c] = acc;
  }
}

// ---------------- gated fusion + classifier + log_softmax ----------------
__global__ __launch_bounds__(256) void k_fusion(const float* __restrict__ nt,
                                                const float* __restrict__ ns,
                                                const float* __restrict__ l1w,
                                                const float* __restrict__ l1b,
                                                const float* __restrict__ l2w,
                                                const float* __restrict__ l2b,
                                                const float* __restrict__ linw,
                                                const float* __restrict__ linb,
                                                float* __restrict__ out) {
  __shared__ float rt[Dw], rs[Dw];
  __shared__ float scr[4];
  int b = blockIdx.x, j = threadIdx.x;
  if (j < Dw) { rt[j] = nt[(size_t)b * Dw + j]; rs[j] = ns[(size_t)b * Dw + j]; }
  __syncthreads();
  float pt = 0.f, ps = 0.f;
  if (j < Dw) {
    float at = l1b[j], as = l1b[j];
    for (int kk = 0; kk < Dw; kk++) {
      float w = l1w[(size_t)kk * Dw + j];
      at += rt[kk] * w;
      as += rs[kk] * w;
    }
    float lw2 = l2w[j];
    pt = tanhf(at) * lw2;
    ps = tanhf(as) * lw2;
  }
  float st = block_sum_256(pt, scr);
  float ss = block_sum_256(ps, scr);
  st += l2b[0]; ss += l2b[0];
  float m = fmaxf(st, ss);
  float e0 = expf(st - m), e1v = expf(ss - m);
  float inv = 1.f / (e0 + e1v);
  float s0 = e0 * inv, s1 = e1v * inv;
  float fj  = (j < Dw) ? (s0 * rt[j] + s1 * rs[j]) : 0.f;
  float w0  = (j < Dw) ? linw[(size_t)j * 2 + 0] : 0.f;
  float w1v = (j < Dw) ? linw[(size_t)j * 2 + 1] : 0.f;
  float l0 = block_sum_256(fj * w0, scr);
  float l1 = block_sum_256(fj * w1v, scr);
  if (j == 0) {
    l0 += linb[0]; l1 += linb[1];
    float mm = fmaxf(l0, l1);
    float lse = mm + logf(expf(l0 - mm) + expf(l1 - mm));
    out[(size_t)b * 2 + 0] = l0 - lse;
    out[(size_t)b * 2 + 1] = l1 - lse;
  }
}

extern "C" void kernel_launch(void* const* d_in, const int* in_sizes, int n_in,
                              void* d_out, int out_size, void* d_ws, size_t ws_size,
                              hipStream_t stream) {
  const int*   data_idx = (const int*)d_in[0];
  const int*   seq      = (const int*)d_in[1];
  const int*   tsmp     = (const int*)d_in[2];
  const int*   ulev     = (const int*)d_in[3];
  const int*   useq     = (const int*)d_in[4];
  const int*   uinf     = (const int*)d_in[5];
  const int*   ucen     = (const int*)d_in[6];
  const float* spread   = (const float*)d_in[7];
  // d_in[8] = id2vector (unused by reference)
  const float* user_emb = (const float*)d_in[9];
  const float* cen_emb  = (const float*)d_in[10];
  const float* time_emb = (const float*)d_in[11];
  const float* pos_emb  = (const float*)d_in[12];
  const float* inf_emb  = (const float*)d_in[13];
  const float* w1       = (const float*)d_in[14];
  const float* w2       = (const float*)d_in[15];
  const float* w3       = (const float*)d_in[16];
  const float* Wm       = (const float*)d_in[17];
  const float* W2m      = (const float*)d_in[18];
  const float* f_l1_w   = (const float*)d_in[19];
  const float* f_l1_b   = (const float*)d_in[20];
  const float* f_l2_w   = (const float*)d_in[21];
  const float* f_l2_b   = (const float*)d_in[22];
  const float* lin_w    = (const float*)d_in[23];
  const float* lin_b    = (const float*)d_in[24];
  const float* t_wq = (const float*)d_in[25];
  const float* t_wk = (const float*)d_in[26];
  const float* t_wv = (const float*)d_in[27];
  const float* t_wo = (const float*)d_in[28];
  const float* t_g  = (const float*)d_in[29];
  const float* t_b  = (const float*)d_in[30];
  const float* s_wq = (const float*)d_in[31];
  const float* s_wk = (const float*)d_in[32];
  const float* s_wv = (const float*)d_in[33];
  const float* s_wo = (const float*)d_in[34];
  const float* s_g  = (const float*)d_in[35];
  const float* s_b  = (const float*)d_in[36];

  char* ws = (char*)d_ws;
  // workspace layout (bytes); aliasing: HIDT/HIDS reuse dead X/EDGE; ATT reuses dead Q
  constexpr size_t SZ_X    = (size_t)Nn * Dd * 4;   // 25.6 MB
  constexpr size_t SZ_E    = (size_t)Ee * Dd * 4;   // 5.12 MB
  constexpr size_t SZ_BLD  = (size_t)BL * Dd * 4;   // 13.1 MB
  constexpr size_t OFF_X    = 8192;
  constexpr size_t OFF_EDGE = OFF_X + SZ_X;
  constexpr size_t OFF_E1   = OFF_EDGE + SZ_E;
  constexpr size_t OFF_HIDT = OFF_X;                 // X/EDGE dead by then
  constexpr size_t OFF_HIDS = OFF_HIDT + SZ_BLD;
  constexpr size_t OFF_NODE = OFF_E1 + SZ_E;
  constexpr size_t OFF_Q    = OFF_NODE + SZ_X;
  constexpr size_t OFF_K    = OFF_Q + SZ_BLD;
  constexpr size_t OFF_V    = OFF_K + SZ_BLD;
  constexpr size_t OFF_CTX  = OFF_V + SZ_BLD;
  constexpr size_t OFF_ATT  = OFF_Q;                 // Q dead after k_attn
  constexpr size_t OFF_NT   = OFF_CTX + SZ_BLD;
  constexpr size_t OFF_NS   = OFF_NT + (size_t)Bb * Dw * 4;

  float* dotb    = (float*)(ws + 0);
  float* nrmb    = (float*)(ws + 3072);
  float* internw = (float*)(ws + 6144);
  float* X    = (float*)(ws + OFF_X);
  float* EDGE = (float*)(ws + OFF_EDGE);
  float* E1   = (float*)(ws + OFF_E1);
  float* HIDT = (float*)(ws + OFF_HIDT);
  float* HIDS = (float*)(ws + OFF_HIDS);
  float* NODE = (float*)(ws + OFF_NODE);
  float* Q    = (float*)(ws + OFF_Q);
  float* K    = (float*)(ws + OFF_K);
  float* V    = (float*)(ws + OFF_V);
  float* CTX  = (float*)(ws + OFF_CTX);
  float* ATT  = (float*)(ws + OFF_ATT);
  float* NT   = (float*)(ws + OFF_NT);
  float* NS   = (float*)(ws + OFF_NS);
  float* outp = (float*)d_out;

  // ---- HGNN ----
  k_cos<<<TVv, 256, 0, stream>>>(w3, dotb, nrmb);
  k_internw<<<1, 256, 0, stream>>>(dotb, nrmb, internw);
  k_mm128<0><<<(Nn + 31) / 32, 256, 0, stream>>>(user_emb, cen_emb, ucen, w1, internw, X, Nn);
  k_gather<true><<<Ee, 128, 0, stream>>>(X, seq, Ll, EDGE);
  k_mm128<1><<<(Ee + 31) / 32, 256, 0, stream>>>(EDGE, nullptr, nullptr, w2, nullptr, E1, Ee);
  k_gather<false><<<Nn, 128, 0, stream>>>(E1, useq, LuU, NODE);

  // ---- attention inputs ----
  k_hidden<<<BL, 128, 0, stream>>>(NODE, data_idx, seq, tsmp, uinf, ulev,
                                   time_emb, inf_emb, pos_emb, HIDT, HIDS);

  // ---- branch t ----
  k_mm128<1><<<BL / 32, 256, 0, stream>>>(HIDT, nullptr, nullptr, t_wq, nullptr, Q, BL);
  k_mm128<1><<<BL / 32, 256, 0, stream>>>(HIDT, nullptr, nullptr, t_wk, nullptr, K, BL);
  k_mm128<1><<<BL / 32, 256, 0, stream>>>(HIDT, nullptr, nullptr, t_wv, nullptr, V, BL);
  k_attn<<<Bb * 8, 64, 0, stream>>>(Q, K, V, data_idx, seq, CTX);
  k_projln<<<BL / 32, 256, 0, stream>>>(CTX, HIDT, t_wo, t_g, t_b, ATT, BL);
  k_news<0><<<Bb, 256, 0, stream>>>(ATT, data_idx, seq, spread, Wm, NT);

  // ---- branch s (reuse Q/K/V/CTX/ATT) ----
  k_mm128<1><<<BL / 32, 256, 0, stream>>>(HIDS, nullptr, nullptr, s_wq, nullptr, Q, BL);
  k_mm128<1><<<BL / 32, 256, 0, stream>>>(HIDS, nullptr, nullptr, s_wk, nullptr, K, BL);
  k_mm128<1><<<BL / 32, 256, 0, stream>>>(HIDS, nullptr, nullptr, s_wv, nullptr, V, BL);
  k_attn<<<Bb * 8, 64, 0, stream>>>(Q, K, V, data_idx, seq, CTX);
  k_projln<<<BL / 32, 256, 0, stream>>>(CTX, HIDS, s_wo, s_g, s_b, ATT, BL);
  k_news<1><<<Bb, 256, 0, stream>>>(ATT, data_idx, seq, spread, W2m, NS);

  // ---- fusion + classifier ----
  k_fusion<<<Bb, 256, 0, stream>>>(NT, NS, f_l1_w, f_l1_b, f_l2_w, f_l2_b,
                                   lin_w, lin_b, outp);

  (void)in_sizes; (void)n_in; (void)out_size; (void)ws_size;
}

// Round 2
// 475.459 us; speedup vs baseline: 1.6651x; 1.6651x over previous
//
#include <hip/hip_runtime.h>
#include <math.h>

// Problem dims (fixed by reference setup_inputs)
constexpr int Nn = 50000;  // nodes
constexpr int Ee = 10000;  // edges
constexpr int Ll = 50;     // seq len
constexpr int LuU = 20;    // user seq len
constexpr int Dd = 128;    // hidden dim
constexpr int Bb = 512;    // batch
constexpr int TVv = 768;   // text-vector dim
constexpr int Dw = 130;    // D+2
constexpr int BL = Bb * Ll; // 25600 rows in attention tensors

typedef __attribute__((ext_vector_type(8))) short bf8v;          // 8 bf16 (MFMA operand)
typedef __attribute__((ext_vector_type(4))) float f4v;           // MFMA acc
typedef __attribute__((ext_vector_type(8))) unsigned short u16x8;

__device__ __forceinline__ unsigned short f2bf(float f) {  // RNE f32->bf16
  union { float f; unsigned u; } v; v.f = f;
  unsigned r = v.u + 0x7FFFu + ((v.u >> 16) & 1u);
  return (unsigned short)(r >> 16);
}
__device__ __forceinline__ float bf2f(unsigned short h) {
  union { unsigned u; float f; } v; v.u = ((unsigned)h) << 16; return v.f;
}
// XOR swizzle within a [rows][256B] bf16 tile: permute 16B slots by row&7 (G4 fix)
__device__ __forceinline__ int swz(int b) { return b ^ (((b >> 8) & 7) << 4); }

// ---------------- block reduction (blockDim.x == 256) ----------------
__device__ __forceinline__ float block_sum_256(float v, volatile float* scr) {
#pragma unroll
  for (int o = 32; o > 0; o >>= 1) v += __shfl_down(v, o, 64);
  __syncthreads();
  if ((threadIdx.x & 63) == 0) scr[threadIdx.x >> 6] = v;
  __syncthreads();
  return scr[0] + scr[1] + scr[2] + scr[3];
}

// ---------------- HGNN: cosine / inter_nw ----------------
__global__ __launch_bounds__(256) void k_cos(const float* __restrict__ w3,
                                             float* __restrict__ dotb,
                                             float* __restrict__ nrmb) {
  __shared__ float scr[4];
  int i = blockIdx.x;
  const float* row = w3 + (size_t)i * TVv;
  float d = 0.f, n = 0.f;
  for (int j = threadIdx.x; j < TVv; j += 256) {
    float a = row[j];
    d += a * w3[j];
    n += a * a;
  }
  d = block_sum_256(d, scr);
  n = block_sum_256(n, scr);
  if (threadIdx.x == 0) { dotb[i] = d; nrmb[i] = n; }
}

__global__ __launch_bounds__(256) void k_internw(const float* __restrict__ dotb,
                                                 const float* __restrict__ nrmb,
                                                 float* __restrict__ internw) {
  __shared__ float scr[4];
  float n0 = sqrtf(nrmb[0]);
  float s = 0.f;
  for (int i = threadIdx.x; i < TVv; i += 256)
    s += dotb[i] / (n0 * sqrtf(nrmb[i]));
  s = block_sum_256(s, scr);
  if (threadIdx.x == 0) *internw = s / (float)TVv;
}

// ---------------- weight prep: f32 [k][n] -> bf16 transposed [n][k] ----------------
__global__ __launch_bounds__(256) void k_prep(
    const float* w1, const float* w2,
    const float* twq, const float* twk, const float* twv, const float* two,
    const float* swq, const float* swk, const float* swv, const float* swo,
    unsigned short* __restrict__ out) {
  int wsel = blockIdx.x >> 3, part = blockIdx.x & 7;
  const float* w;
  switch (wsel) {
    case 0: w = w1; break;  case 1: w = w2; break;
    case 2: w = twq; break; case 3: w = twk; break;
    case 4: w = twv; break; case 5: w = two; break;
    case 6: w = swq; break; case 7: w = swk; break;
    case 8: w = swv; break; default: w = swo; break;
  }
  int u = part * 256 + threadIdx.x;          // [0,2048)
  int n = u >> 4, k0 = (u & 15) * 8;
  u16x8 pv;
#pragma unroll
  for (int i = 0; i < 8; i++) pv[i] = f2bf(w[(size_t)(k0 + i) * Dd + n]);
  ((u16x8*)(out + (size_t)wsel * Dd * Dd))[u] = pv;
}

// ---------------- MFMA GEMM: out[r][:] = rowIn[r] @ W  (W pre-transposed bf16) ----
// MODE 0: rowIn = (user_emb[r] + cen_emb[gidx[r]]) * scale   (f32 sources)
// MODE 1: rowIn = bf16 input rows
// LN: fused  out = LayerNorm(gemm + resid) * g + b  (f32 out); else bf16 out
template <int MODE, bool LN>
__global__ __launch_bounds__(256) void k_gemm(
    const void* __restrict__ inA, const float* __restrict__ in1,
    const int* __restrict__ gidx, const float* __restrict__ scalep,
    const unsigned short* __restrict__ WTg,
    const float* __restrict__ resid, const float* __restrict__ lng,
    const float* __restrict__ lnb, void* __restrict__ outp, int nrows) {
  __shared__ unsigned short WT[Dd * Dd];                    // 32 KB, swizzled
  __shared__ __align__(16) char UB[LN ? (64 * 132 * 4) : (64 * Dd * 2)];
  unsigned short* Ab = (unsigned short*)UB;
  float (*O)[132] = (float (*)[132])UB;

  int tid = threadIdx.x;
  {
    const u16x8* src = (const u16x8*)WTg;
    for (int u = tid; u < 2048; u += 256)
      *(u16x8*)((char*)WT + swz(u * 16)) = src[u];
  }
  int r0 = blockIdx.x * 64;
  if constexpr (MODE == 0) {
    float sc = *scalep;
    for (int u = tid; u < 1024; u += 256) {
      int rr = u >> 4, c0 = (u & 15) * 8;
      int r = r0 + rr;
      u16x8 pv;
      if (r < nrows) {
        const float* a = (const float*)inA + (size_t)r * Dd + c0;
        const float* c = in1 + (size_t)gidx[r] * Dd + c0;
#pragma unroll
        for (int i = 0; i < 8; i++) pv[i] = f2bf((a[i] + c[i]) * sc);
      } else {
#pragma unroll
        for (int i = 0; i < 8; i++) pv[i] = 0;
      }
      *(u16x8*)((char*)Ab + swz(rr * 256 + c0 * 2)) = pv;
    }
  } else {
    const u16x8* src = (const u16x8*)inA;
    for (int u = tid; u < 1024; u += 256) {
      int rr = u >> 4;
      int r = r0 + rr;
      u16x8 pv;
      if (r < nrows) pv = src[(size_t)r * 16 + (u & 15)];
      else {
#pragma unroll
        for (int i = 0; i < 8; i++) pv[i] = 0;
      }
      *(u16x8*)((char*)Ab + swz(rr * 256 + (u & 15) * 16)) = pv;
    }
  }
  __syncthreads();

  int lane = tid & 63, wid = tid >> 6;
  int lrow = lane & 15, lg = lane >> 4;
  bf8v af[4];
#pragma unroll
  for (int kc = 0; kc < 4; kc++)
    af[kc] = *(const bf8v*)((char*)Ab + swz((wid * 16 + lrow) * 256 + kc * 64 + lg * 16));
  f4v acc[8];
#pragma unroll
  for (int nt = 0; nt < 8; nt++)
#pragma unroll
    for (int j = 0; j < 4; j++) acc[nt][j] = 0.f;
#pragma unroll
  for (int nt = 0; nt < 8; nt++) {
#pragma unroll
    for (int kc = 0; kc < 4; kc++) {
      bf8v bfg = *(const bf8v*)((char*)WT + swz((nt * 16 + lrow) * 256 + kc * 64 + lg * 16));
      acc[nt] = __builtin_amdgcn_mfma_f32_16x16x32_bf16(af[kc], bfg, acc[nt], 0, 0, 0);
    }
  }

  if constexpr (!LN) {
    unsigned short* out = (unsigned short*)outp;
#pragma unroll
    for (int nt = 0; nt < 8; nt++) {
#pragma unroll
      for (int j = 0; j < 4; j++) {
        int r = r0 + wid * 16 + lg * 4 + j;                  // C/D: row=(l>>4)*4+j
        if (r < nrows) out[(size_t)r * Dd + nt * 16 + lrow] = f2bf(acc[nt][j]);
      }
    }
  } else {
    __syncthreads();   // all A reads done before O overwrites the union buffer
#pragma unroll
    for (int nt = 0; nt < 8; nt++)
#pragma unroll
      for (int j = 0; j < 4; j++)
        O[wid * 16 + lg * 4 + j][nt * 16 + lrow] = acc[nt][j];
    __syncthreads();
    int r = tid >> 2, c0 = (tid & 3) * 32;
    size_t gr = (size_t)(r0 + r);
    float vv[32];
    float s1 = 0.f, s2 = 0.f;
#pragma unroll
    for (int i = 0; i < 32; i++) {
      float x = O[r][c0 + i] + resid[gr * Dd + c0 + i];
      vv[i] = x; s1 += x; s2 += x * x;
    }
    s1 += __shfl_xor(s1, 1, 64); s2 += __shfl_xor(s2, 1, 64);
    s1 += __shfl_xor(s1, 2, 64); s2 += __shfl_xor(s2, 2, 64);
    float mu = s1 * (1.f / Dd);
    float var = s2 * (1.f / Dd) - mu * mu;
    float rs = rsqrtf(var + 1e-6f);
    float* out = (float*)outp;
#pragma unroll
    for (int i = 0; i < 32; i++) {
      int c = c0 + i;
      out[gr * Dd + c] = (vv[i] - mu) * rs * lng[c] + lnb[c];
    }
  }
}

// ---------------- edge gather: EDGE = relu(mean over nonpad of X[seq]) (bf16) ----
__global__ __launch_bounds__(128) void k_gather_e(const unsigned short* __restrict__ X,
                                                  const int* __restrict__ seq,
                                                  unsigned short* __restrict__ EDGE) {
  int r = blockIdx.x, c = threadIdx.x;
  const int* row = seq + (size_t)r * Ll;
  float acc = 0.f; int cnt = 0;
  for (int l = 0; l < Ll; l++) {
    int id = row[l];
    if (id > 0) { acc += bf2f(X[(size_t)id * Dd + c]); cnt++; }
  }
  float v = cnt ? acc / (float)cnt : bf2f(X[c]);
  v = fmaxf(v, 0.f);
  EDGE[(size_t)r * Dd + c] = f2bf(v);
}

// ---------------- fused node-gather + hidden build ----------------
__global__ __launch_bounds__(128) void k_hidfuse(
    const unsigned short* __restrict__ E1, const int* __restrict__ data_idx,
    const int* __restrict__ seq, const int* __restrict__ tsmp,
    const int* __restrict__ uinf, const int* __restrict__ ulev,
    const int* __restrict__ useq,
    const float* __restrict__ time_emb, const float* __restrict__ inf_emb,
    const float* __restrict__ pos_emb,
    float* __restrict__ hidT, float* __restrict__ hidS,
    unsigned short* __restrict__ hidTb, unsigned short* __restrict__ hidSb) {
  int bl = blockIdx.x;
  int b = bl / Ll, l = bl % Ll;
  int c = threadIdx.x;
  int e = data_idx[b];
  int sid = seq[(size_t)e * Ll + l];
  const int* urow = useq + (size_t)sid * LuU;
  float acc = 0.f; int cnt = 0;
  for (int t = 0; t < LuU; t++) {
    int eid = urow[t];
    if (eid > 0) { acc += bf2f(E1[(size_t)eid * Dd + c]); cnt++; }
  }
  float node = cnt ? acc / (float)cnt : bf2f(E1[c]);
  int ts = tsmp[(size_t)e * Ll + l];
  int fi = uinf[(size_t)e * Ll + l];
  int lv = ulev[(size_t)e * Ll + l];
  float ht = node + time_emb[(size_t)ts * Dd + c];
  float hs = node + inf_emb[(size_t)fi * Dd + c] + pos_emb[(size_t)lv * Dd + c];
  size_t o = (size_t)bl * Dd + c;
  hidT[o] = ht; hidTb[o] = f2bf(ht);
  hidS[o] = hs; hidSb[o] = f2bf(hs);
}

// ---------------- per-(b,h) attention (bf16 in/out) ----------------
__global__ __launch_bounds__(64) void k_attn(const unsigned short* __restrict__ q,
                                             const unsigned short* __restrict__ k,
                                             const unsigned short* __restrict__ v,
                                             const int* __restrict__ data_idx,
                                             const int* __restrict__ seq,
                                             unsigned short* __restrict__ ctx) {
  int b = blockIdx.x >> 3, h = blockIdx.x & 7;
  __shared__ float Kl[Ll][16], Vl[Ll][16];
  __shared__ int maskl[Ll];
  int e = data_idx[b];
  for (int i = threadIdx.x; i < Ll; i += 64)
    maskl[i] = (seq[(size_t)e * Ll + i] == 0);
  size_t base = (size_t)b * Ll * Dd + h * 16;
  for (int i = threadIdx.x; i < Ll * 16; i += 64) {
    int l = i >> 4, d = i & 15;
    size_t o = base + (size_t)l * Dd + d;
    Kl[l][d] = bf2f(k[o]);
    Vl[l][d] = bf2f(v[o]);
  }
  __syncthreads();
  int qi = threadIdx.x;
  if (qi < Ll) {
    size_t qo = base + (size_t)qi * Dd;
    const u16x8* qp = (const u16x8*)(q + qo);
    u16x8 q0 = qp[0], q1 = qp[1];
    float qv[16];
#pragma unroll
    for (int d = 0; d < 8; d++) { qv[d] = bf2f(q0[d]); qv[8 + d] = bf2f(q1[d]); }
    float sc[Ll];
    float m = -1e30f;
#pragma unroll
    for (int ki = 0; ki < Ll; ki++) {
      float s;
      if (maskl[ki]) s = -1e9f;
      else {
        s = 0.f;
#pragma unroll
        for (int d = 0; d < 16; d++) s += qv[d] * Kl[ki][d];
        s *= 0.25f;
      }
      sc[ki] = s;
      m = fmaxf(m, s);
    }
    float sum = 0.f;
#pragma unroll
    for (int ki = 0; ki < Ll; ki++) { float p = expf(sc[ki] - m); sc[ki] = p; sum += p; }
    float inv = 1.f / sum;
    float o[16];
#pragma unroll
    for (int d = 0; d < 16; d++) o[d] = 0.f;
#pragma unroll
    for (int ki = 0; ki < Ll; ki++) {
      float p = sc[ki];
#pragma unroll
      for (int d = 0; d < 16; d++) o[d] += p * Vl[ki][d];
    }
    unsigned* cp = (unsigned*)(ctx + qo);
#pragma unroll
    for (int d2 = 0; d2 < 8; d2++) {
      unsigned lo = f2bf(o[2 * d2] * inv), hi = f2bf(o[2 * d2 + 1] * inv);
      cp[d2] = lo | (hi << 16);
    }
  }
}

// ---------------- news = (nor_b-weighted sum of att) ++ extras, then @ W ----------
template <int BR>
__global__ __launch_bounds__(256) void k_news(const float* __restrict__ att,
                                              const int* __restrict__ data_idx,
                                              const int* __restrict__ seq,
                                              const float* __restrict__ spread,
                                              const float* __restrict__ W,
                                              float* __restrict__ out) {
  __shared__ float row[Dw];
  int b = blockIdx.x;
  int e = data_idx[b];
  const int* sb = seq + (size_t)e * Ll;
  int cnt = 0;
  for (int l = 0; l < Ll; l++) cnt += (sb[l] > 0);
  int c = threadIdx.x;
  if (c < Dd) {
    float acc = 0.f;
    if (cnt > 0) {
      for (int l = 0; l < Ll; l++)
        if (sb[l] > 0) acc += att[((size_t)b * Ll + l) * Dd + c];
      acc /= (float)cnt;
    } else {
      for (int l = 0; l < Ll; l++) acc += att[((size_t)b * Ll + l) * Dd + c];
      acc *= (1.f / (float)Ll);
    }
    row[c] = acc;
  } else if (c < Dw) {
    int cc = c - Dd;
    row[c] = (BR == 0) ? spread[(size_t)e * 4 + 2 + cc] * (1.f / 86400.f)
                       : spread[(size_t)e * 4 + cc];
  }
  __syncthreads();
  if (c < Dw) {
    float acc = 0.f;
    for (int kk = 0; kk < Dw; kk++) acc += row[kk] * W[(size_t)kk * Dw + c];
    out[(size_t)b * Dw + c] = acc;
  }
}

// ---------------- gated fusion + classifier + log_softmax ----------------
__global__ __launch_bounds__(256) void k_fusion(const float* __restrict__ nt,
                                                const float* __restrict__ ns,
                                                const float* __restrict__ l1w,
                                                const float* __restrict__ l1b,
                                                const float* __restrict__ l2w,
                                                const float* __restrict__ l2b,
                                                const float* __restrict__ linw,
                                                const float* __restrict__ linb,
                                                float* __restrict__ out) {
  __shared__ float rt[Dw], rs[Dw];
  __shared__ float scr[4];
  int b = blockIdx.x, j = threadIdx.x;
  if (j < Dw) { rt[j] = nt[(size_t)b * Dw + j]; rs[j] = ns[(size_t)b * Dw + j]; }
  __syncthreads();
  float pt = 0.f, ps = 0.f;
  if (j < Dw) {
    float at = l1b[j], as = l1b[j];
    for (int kk = 0; kk < Dw; kk++) {
      float w = l1w[(size_t)kk * Dw + j];
      at += rt[kk] * w;
      as += rs[kk] * w;
    }
    float lw2 = l2w[j];
    pt = tanhf(at) * lw2;
    ps = tanhf(as) * lw2;
  }
  float st = block_sum_256(pt, scr);
  float ss = block_sum_256(ps, scr);
  st += l2b[0]; ss += l2b[0];
  float m = fmaxf(st, ss);
  float e0 = expf(st - m), e1v = expf(ss - m);
  float inv = 1.f / (e0 + e1v);
  float s0 = e0 * inv, s1 = e1v * inv;
  float fj  = (j < Dw) ? (s0 * rt[j] + s1 * rs[j]) : 0.f;
  float w0  = (j < Dw) ? linw[(size_t)j * 2 + 0] : 0.f;
  float w1v = (j < Dw) ? linw[(size_t)j * 2 + 1] : 0.f;
  float l0 = block_sum_256(fj * w0, scr);
  float l1 = block_sum_256(fj * w1v, scr);
  if (j == 0) {
    l0 += linb[0]; l1 += linb[1];
    float mm = fmaxf(l0, l1);
    float lse = mm + logf(expf(l0 - mm) + expf(l1 - mm));
    out[(size_t)b * 2 + 0] = l0 - lse;
    out[(size_t)b * 2 + 1] = l1 - lse;
  }
}

extern "C" void kernel_launch(void* const* d_in, const int* in_sizes, int n_in,
                              void* d_out, int out_size, void* d_ws, size_t ws_size,
                              hipStream_t stream) {
  const int*   data_idx = (const int*)d_in[0];
  const int*   seq      = (const int*)d_in[1];
  const int*   tsmp     = (const int*)d_in[2];
  const int*   ulev     = (const int*)d_in[3];
  const int*   useq     = (const int*)d_in[4];
  const int*   uinf     = (const int*)d_in[5];
  const int*   ucen     = (const int*)d_in[6];
  const float* spread   = (const float*)d_in[7];
  const float* user_emb = (const float*)d_in[9];
  const float* cen_emb  = (const float*)d_in[10];
  const float* time_emb = (const float*)d_in[11];
  const float* pos_emb  = (const float*)d_in[12];
  const float* inf_emb  = (const float*)d_in[13];
  const float* w1       = (const float*)d_in[14];
  const float* w2       = (const float*)d_in[15];
  const float* w3       = (const float*)d_in[16];
  const float* Wm       = (const float*)d_in[17];
  const float* W2m      = (const float*)d_in[18];
  const float* f_l1_w   = (const float*)d_in[19];
  const float* f_l1_b   = (const float*)d_in[20];
  const float* f_l2_w   = (const float*)d_in[21];
  const float* f_l2_b   = (const float*)d_in[22];
  const float* lin_w    = (const float*)d_in[23];
  const float* lin_b    = (const float*)d_in[24];
  const float* t_wq = (const float*)d_in[25];
  const float* t_wk = (const float*)d_in[26];
  const float* t_wv = (const float*)d_in[27];
  const float* t_wo = (const float*)d_in[28];
  const float* t_g  = (const float*)d_in[29];
  const float* t_b  = (const float*)d_in[30];
  const float* s_wq = (const float*)d_in[31];
  const float* s_wk = (const float*)d_in[32];
  const float* s_wv = (const float*)d_in[33];
  const float* s_wo = (const float*)d_in[34];
  const float* s_g  = (const float*)d_in[35];
  const float* s_b  = (const float*)d_in[36];

  char* ws = (char*)d_ws;
  constexpr size_t SZ_WT  = (size_t)10 * Dd * Dd * 2;   // 10 transposed bf16 weights
  constexpr size_t SZ_XB  = (size_t)Nn * Dd * 2;
  constexpr size_t SZ_EB  = (size_t)Ee * Dd * 2;
  constexpr size_t SZ_BF  = (size_t)BL * Dd * 4;
  constexpr size_t SZ_BH  = (size_t)BL * Dd * 2;
  constexpr size_t OFF_WT  = 8192;
  constexpr size_t OFF_X   = OFF_WT + SZ_WT;
  constexpr size_t OFF_EDGE= OFF_X + SZ_XB;
  constexpr size_t OFF_E1  = OFF_EDGE + SZ_EB;
  constexpr size_t OFF_HT  = OFF_E1 + SZ_EB;
  constexpr size_t OFF_HS  = OFF_HT + SZ_BF;
  constexpr size_t OFF_HTB = OFF_HS + SZ_BF;
  constexpr size_t OFF_HSB = OFF_HTB + SZ_BH;
  constexpr size_t OFF_Q   = OFF_HSB + SZ_BH;
  constexpr size_t OFF_K   = OFF_Q + SZ_BH;
  constexpr size_t OFF_V   = OFF_K + SZ_BH;
  constexpr size_t OFF_CTX = OFF_V + SZ_BH;
  constexpr size_t OFF_ATT = OFF_CTX + SZ_BH;
  constexpr size_t OFF_NT  = OFF_ATT + SZ_BF;
  constexpr size_t OFF_NS  = OFF_NT + (size_t)Bb * Dw * 4;

  float* dotb    = (float*)(ws + 0);
  float* nrmb    = (float*)(ws + 3072);
  float* internw = (float*)(ws + 6144);
  unsigned short* WTall = (unsigned short*)(ws + OFF_WT);
  unsigned short* Xb    = (unsigned short*)(ws + OFF_X);
  unsigned short* EDGEb = (unsigned short*)(ws + OFF_EDGE);
  unsigned short* E1b   = (unsigned short*)(ws + OFF_E1);
  float*          HIDT  = (float*)(ws + OFF_HT);
  float*          HIDS  = (float*)(ws + OFF_HS);
  unsigned short* HIDTb = (unsigned short*)(ws + OFF_HTB);
  unsigned short* HIDSb = (unsigned short*)(ws + OFF_HSB);
  unsigned short* Qb    = (unsigned short*)(ws + OFF_Q);
  unsigned short* Kb    = (unsigned short*)(ws + OFF_K);
  unsigned short* Vb    = (unsigned short*)(ws + OFF_V);
  unsigned short* CTXb  = (unsigned short*)(ws + OFF_CTX);
  float*          ATT   = (float*)(ws + OFF_ATT);
  float*          NT    = (float*)(ws + OFF_NT);
  float*          NS    = (float*)(ws + OFF_NS);
  float* outp = (float*)d_out;

  const unsigned short* WT_w1  = WTall + 0 * Dd * Dd;
  const unsigned short* WT_w2  = WTall + 1 * Dd * Dd;
  const unsigned short* WT_twq = WTall + 2 * Dd * Dd;
  const unsigned short* WT_twk = WTall + 3 * Dd * Dd;
  const unsigned short* WT_twv = WTall + 4 * Dd * Dd;
  const unsigned short* WT_two = WTall + 5 * Dd * Dd;
  const unsigned short* WT_swq = WTall + 6 * Dd * Dd;
  const unsigned short* WT_swk = WTall + 7 * Dd * Dd;
  const unsigned short* WT_swv = WTall + 8 * Dd * Dd;
  const unsigned short* WT_swo = WTall + 9 * Dd * Dd;

  // ---- prep ----
  k_prep<<<80, 256, 0, stream>>>(w1, w2, t_wq, t_wk, t_wv, t_wo,
                                 s_wq, s_wk, s_wv, s_wo, WTall);
  k_cos<<<TVv, 256, 0, stream>>>(w3, dotb, nrmb);
  k_internw<<<1, 256, 0, stream>>>(dotb, nrmb, internw);

  // ---- HGNN ----
  int tilesN = (Nn + 63) / 64;   // 782
  int tilesE = (Ee + 63) / 64;   // 157
  int tilesB = BL / 64;          // 400
  k_gemm<0, false><<<tilesN, 256, 0, stream>>>(user_emb, cen_emb, ucen, internw,
                                               WT_w1, nullptr, nullptr, nullptr, Xb, Nn);
  k_gather_e<<<Ee, 128, 0, stream>>>(Xb, seq, EDGEb);
  k_gemm<1, false><<<tilesE, 256, 0, stream>>>(EDGEb, nullptr, nullptr, nullptr,
                                               WT_w2, nullptr, nullptr, nullptr, E1b, Ee);
  k_hidfuse<<<BL, 128, 0, stream>>>(E1b, data_idx, seq, tsmp, uinf, ulev, useq,
                                    time_emb, inf_emb, pos_emb,
                                    HIDT, HIDS, HIDTb, HIDSb);

  // ---- branch t ----
  k_gemm<1, false><<<tilesB, 256, 0, stream>>>(HIDTb, nullptr, nullptr, nullptr,
                                               WT_twq, nullptr, nullptr, nullptr, Qb, BL);
  k_gemm<1, false><<<tilesB, 256, 0, stream>>>(HIDTb, nullptr, nullptr, nullptr,
                                               WT_twk, nullptr, nullptr, nullptr, Kb, BL);
  k_gemm<1, false><<<tilesB, 256, 0, stream>>>(HIDTb, nullptr, nullptr, nullptr,
                                               WT_twv, nullptr, nullptr, nullptr, Vb, BL);
  k_attn<<<Bb * 8, 64, 0, stream>>>(Qb, Kb, Vb, data_idx, seq, CTXb);
  k_gemm<1, true><<<tilesB, 256, 0, stream>>>(CTXb, nullptr, nullptr, nullptr,
                                              WT_two, HIDT, t_g, t_b, ATT, BL);
  k_news<0><<<Bb, 256, 0, stream>>>(ATT, data_idx, seq, spread, Wm, NT);

  // ---- branch s ----
  k_gemm<1, false><<<tilesB, 256, 0, stream>>>(HIDSb, nullptr, nullptr, nullptr,
                                               WT_swq, nullptr, nullptr, nullptr, Qb, BL);
  k_gemm<1, false><<<tilesB, 256, 0, stream>>>(HIDSb, nullptr, nullptr, nullptr,
                                               WT_swk, nullptr, nullptr, nullptr, Kb, BL);
  k_gemm<1, false><<<tilesB, 256, 0, stream>>>(HIDSb, nullptr, nullptr, nullptr,
                                               WT_swv, nullptr, nullptr, nullptr, Vb, BL);
  k_attn<<<Bb * 8, 64, 0, stream>>>(Qb, Kb, Vb, data_idx, seq, CTXb);
  k_gemm<1, true><<<tilesB, 256, 0, stream>>>(CTXb, nullptr, nullptr, nullptr,
                                              WT_swo, HIDS, s_g, s_b, ATT, BL);
  k_news<1><<<Bb, 256, 0, stream>>>(ATT, data_idx, seq, spread, W2m, NS);

  // ---- fusion + classifier ----
  k_fusion<<<Bb, 256, 0, stream>>>(NT, NS, f_l1_w, f_l1_b, f_l2_w, f_l2_b,
                                   lin_w, lin_b, outp);

  (void)in_sizes; (void)n_in; (void)out_size; (void)ws_size; (void)w3;
}

// Round 3
// 369.147 us; speedup vs baseline: 2.1447x; 1.2880x over previous
//
#include <hip/hip_runtime.h>
#include <math.h>

constexpr int Nn = 50000;
constexpr int Ee = 10000;
constexpr int Ll = 50;
constexpr int LuU = 20;
constexpr int Dd = 128;
constexpr int Bb = 512;
constexpr int TVv = 768;
constexpr int Dw = 130;
constexpr int BL = Bb * Ll;   // 25600

typedef __attribute__((ext_vector_type(8))) short bf8v;
typedef __attribute__((ext_vector_type(4))) float f4v;
typedef __attribute__((ext_vector_type(8))) unsigned short u16x8;

__device__ __forceinline__ unsigned short f2bf(float f) {
  union { float f; unsigned u; } v; v.f = f;
  unsigned r = v.u + 0x7FFFu + ((v.u >> 16) & 1u);
  return (unsigned short)(r >> 16);
}
__device__ __forceinline__ float bf2f(unsigned short h) {
  union { unsigned u; float f; } v; v.u = ((unsigned)h) << 16; return v.f;
}
__device__ __forceinline__ int swz(int b) { return b ^ (((b >> 8) & 7) << 4); }

// ---------------- block reduction ----------------
__device__ __forceinline__ float block_sum_256(float v, volatile float* scr) {
#pragma unroll
  for (int o = 32; o > 0; o >>= 1) v += __shfl_down(v, o, 64);
  __syncthreads();
  if ((threadIdx.x & 63) == 0) scr[threadIdx.x >> 6] = v;
  __syncthreads();
  return scr[0] + scr[1] + scr[2] + scr[3];
}

// ---------------- cosine / inter_nw ----------------
__global__ __launch_bounds__(256) void k_cos(const float* __restrict__ w3,
                                             float* __restrict__ dotb,
                                             float* __restrict__ nrmb) {
  __shared__ float scr[4];
  int i = blockIdx.x;
  const float* row = w3 + (size_t)i * TVv;
  float d = 0.f, n = 0.f;
  for (int j = threadIdx.x; j < TVv; j += 256) {
    float a = row[j];
    d += a * w3[j];
    n += a * a;
  }
  d = block_sum_256(d, scr);
  n = block_sum_256(n, scr);
  if (threadIdx.x == 0) { dotb[i] = d; nrmb[i] = n; }
}

__global__ __launch_bounds__(256) void k_internw(const float* __restrict__ dotb,
                                                 const float* __restrict__ nrmb,
                                                 float* __restrict__ internw) {
  __shared__ float scr[4];
  float n0 = sqrtf(nrmb[0]);
  float s = 0.f;
  for (int i = threadIdx.x; i < TVv; i += 256)
    s += dotb[i] / (n0 * sqrtf(nrmb[i]));
  s = block_sum_256(s, scr);
  if (threadIdx.x == 0) *internw = s / (float)TVv;
}

// ---------------- weight prep: f32 [k][n] -> bf16 [n][k] ----------------
__global__ __launch_bounds__(256) void k_prep(
    const float* w1, const float* w2,
    const float* twq, const float* twk, const float* twv, const float* two,
    const float* swq, const float* swk, const float* swv, const float* swo,
    unsigned short* __restrict__ out) {
  int wsel = blockIdx.x >> 3, part = blockIdx.x & 7;
  const float* w;
  switch (wsel) {
    case 0: w = w1; break;  case 1: w = w2; break;
    case 2: w = twq; break; case 3: w = twk; break;
    case 4: w = twv; break; case 5: w = two; break;
    case 6: w = swq; break; case 7: w = swk; break;
    case 8: w = swv; break; default: w = swo; break;
  }
  int u = part * 256 + threadIdx.x;
  int n = u >> 4, k0 = (u & 15) * 8;
  u16x8 pv;
#pragma unroll
  for (int i = 0; i < 8; i++) pv[i] = f2bf(w[(size_t)(k0 + i) * Dd + n]);
  ((u16x8*)(out + (size_t)wsel * Dd * Dd))[u] = pv;
}

// ---------------- MFMA GEMM (plain, bf16 out) ----------------
// MODE 0: X GEMM   in=(user_emb+cen_emb[gidx])*scale (f32)  out0, nrows=Nn
// MODE 1: E1 GEMM  in=EDGEb                                 out0, nrows=Ee
// MODE 2: QKV both branches; grid = 400*6; derives ptrs     nrows=BL
template <int MODE>
__global__ __launch_bounds__(256) void k_gemm_plain(
    const void* __restrict__ inA, const float* __restrict__ in1,
    const int* __restrict__ gidx, const float* __restrict__ scalep,
    const unsigned short* __restrict__ WTbase,
    const unsigned short* __restrict__ hidT, const unsigned short* __restrict__ hidS,
    unsigned short* __restrict__ outQ, unsigned short* __restrict__ outK,
    unsigned short* __restrict__ outV,
    unsigned short* __restrict__ out0, int nrows) {
  __shared__ unsigned short WT[Dd * Dd];           // 32 KB swizzled
  __shared__ __align__(16) unsigned short Ab[64 * Dd];

  const unsigned short* Wg;
  const unsigned short* in;
  unsigned short* out;
  int r0;
  if constexpr (MODE == 2) {
    int tile = blockIdx.x % 400, z = blockIdx.x / 400;
    int branch = z / 3, sel = z % 3;
    in = branch ? hidS : hidT;
    Wg = WTbase + (size_t)(2 + branch * 4 + sel) * Dd * Dd;
    unsigned short* o = (sel == 0) ? outQ : (sel == 1) ? outK : outV;
    out = o + (size_t)branch * BL * Dd;
    r0 = tile * 64;
  } else {
    in = (const unsigned short*)inA;
    Wg = WTbase + (size_t)(MODE == 0 ? 0 : 1) * Dd * Dd;
    out = out0;
    r0 = blockIdx.x * 64;
  }

  int tid = threadIdx.x;
  {
    const u16x8* src = (const u16x8*)Wg;
    for (int u = tid; u < 2048; u += 256)
      *(u16x8*)((char*)WT + swz(u * 16)) = src[u];
  }
  if constexpr (MODE == 0) {
    float sc = *scalep;
    for (int u = tid; u < 1024; u += 256) {
      int rr = u >> 4, c0 = (u & 15) * 8;
      int r = r0 + rr;
      u16x8 pv;
      if (r < nrows) {
        const float* a = (const float*)inA + (size_t)r * Dd + c0;
        const float* c = in1 + (size_t)gidx[r] * Dd + c0;
#pragma unroll
        for (int i = 0; i < 8; i++) pv[i] = f2bf((a[i] + c[i]) * sc);
      } else {
#pragma unroll
        for (int i = 0; i < 8; i++) pv[i] = 0;
      }
      *(u16x8*)((char*)Ab + swz(rr * 256 + c0 * 2)) = pv;
    }
  } else {
    for (int u = tid; u < 1024; u += 256) {
      int rr = u >> 4;
      int r = r0 + rr;
      u16x8 pv;
      if (r < nrows) pv = ((const u16x8*)in)[(size_t)r * 16 + (u & 15)];
      else {
#pragma unroll
        for (int i = 0; i < 8; i++) pv[i] = 0;
      }
      *(u16x8*)((char*)Ab + swz(rr * 256 + (u & 15) * 16)) = pv;
    }
  }
  __syncthreads();

  int lane = tid & 63, wid = tid >> 6;
  int lrow = lane & 15, lg = lane >> 4;
  bf8v af[4];
#pragma unroll
  for (int kc = 0; kc < 4; kc++)
    af[kc] = *(const bf8v*)((char*)Ab + swz((wid * 16 + lrow) * 256 + kc * 64 + lg * 16));
  f4v acc[8];
#pragma unroll
  for (int nt = 0; nt < 8; nt++)
#pragma unroll
    for (int j = 0; j < 4; j++) acc[nt][j] = 0.f;
#pragma unroll
  for (int nt = 0; nt < 8; nt++)
#pragma unroll
    for (int kc = 0; kc < 4; kc++) {
      bf8v bfg = *(const bf8v*)((char*)WT + swz((nt * 16 + lrow) * 256 + kc * 64 + lg * 16));
      acc[nt] = __builtin_amdgcn_mfma_f32_16x16x32_bf16(af[kc], bfg, acc[nt], 0, 0, 0);
    }
#pragma unroll
  for (int nt = 0; nt < 8; nt++)
#pragma unroll
    for (int j = 0; j < 4; j++) {
      int r = r0 + wid * 16 + lg * 4 + j;
      if (r < nrows) out[(size_t)r * Dd + nt * 16 + lrow] = f2bf(acc[nt][j]);
    }
}

// ---------------- MFMA GEMM + residual + LayerNorm (both branches) ----------------
__global__ __launch_bounds__(256) void k_gemm_ln(
    const unsigned short* __restrict__ ctxall,
    const unsigned short* __restrict__ hidT, const unsigned short* __restrict__ hidS,
    const unsigned short* __restrict__ WTbase,
    const float* __restrict__ tg, const float* __restrict__ tb,
    const float* __restrict__ sg, const float* __restrict__ sb_,
    unsigned short* __restrict__ attall) {
  __shared__ unsigned short WT[Dd * Dd];
  __shared__ __align__(16) char UB[64 * 132 * 4];
  unsigned short* Ab = (unsigned short*)UB;
  float (*O)[132] = (float (*)[132])UB;

  int tile = blockIdx.x % 400, branch = blockIdx.x / 400;
  const unsigned short* in = ctxall + (size_t)branch * BL * Dd;
  const unsigned short* resid = (branch ? hidS : hidT);
  const unsigned short* Wg = WTbase + (size_t)(5 + branch * 4) * Dd * Dd;
  const float* lng = branch ? sg : tg;
  const float* lnb = branch ? sb_ : tb;
  unsigned short* out = attall + (size_t)branch * BL * Dd;
  int r0 = tile * 64;
  int tid = threadIdx.x;

  {
    const u16x8* src = (const u16x8*)Wg;
    for (int u = tid; u < 2048; u += 256)
      *(u16x8*)((char*)WT + swz(u * 16)) = src[u];
  }
  for (int u = tid; u < 1024; u += 256) {
    int rr = u >> 4;
    u16x8 pv = ((const u16x8*)in)[(size_t)(r0 + rr) * 16 + (u & 15)];
    *(u16x8*)((char*)Ab + swz(rr * 256 + (u & 15) * 16)) = pv;
  }
  __syncthreads();

  int lane = tid & 63, wid = tid >> 6;
  int lrow = lane & 15, lg = lane >> 4;
  bf8v af[4];
#pragma unroll
  for (int kc = 0; kc < 4; kc++)
    af[kc] = *(const bf8v*)((char*)Ab + swz((wid * 16 + lrow) * 256 + kc * 64 + lg * 16));
  f4v acc[8];
#pragma unroll
  for (int nt = 0; nt < 8; nt++)
#pragma unroll
    for (int j = 0; j < 4; j++) acc[nt][j] = 0.f;
#pragma unroll
  for (int nt = 0; nt < 8; nt++)
#pragma unroll
    for (int kc = 0; kc < 4; kc++) {
      bf8v bfg = *(const bf8v*)((char*)WT + swz((nt * 16 + lrow) * 256 + kc * 64 + lg * 16));
      acc[nt] = __builtin_amdgcn_mfma_f32_16x16x32_bf16(af[kc], bfg, acc[nt], 0, 0, 0);
    }
  __syncthreads();
#pragma unroll
  for (int nt = 0; nt < 8; nt++)
#pragma unroll
    for (int j = 0; j < 4; j++)
      O[wid * 16 + lg * 4 + j][nt * 16 + lrow] = acc[nt][j];
  __syncthreads();
  int r = tid >> 2, c0 = (tid & 3) * 32;
  size_t gr = (size_t)(r0 + r);
  float vv[32];
  float s1 = 0.f, s2 = 0.f;
#pragma unroll
  for (int i8 = 0; i8 < 4; i8++) {
    u16x8 hb = *(const u16x8*)(resid + gr * Dd + c0 + i8 * 8);
#pragma unroll
    for (int i = 0; i < 8; i++) {
      float x = O[r][c0 + i8 * 8 + i] + bf2f(hb[i]);
      vv[i8 * 8 + i] = x; s1 += x; s2 += x * x;
    }
  }
  s1 += __shfl_xor(s1, 1, 64); s2 += __shfl_xor(s2, 1, 64);
  s1 += __shfl_xor(s1, 2, 64); s2 += __shfl_xor(s2, 2, 64);
  float mu = s1 * (1.f / Dd);
  float var = s2 * (1.f / Dd) - mu * mu;
  float rs = rsqrtf(var + 1e-6f);
#pragma unroll
  for (int i8 = 0; i8 < 4; i8++) {
    u16x8 ov;
#pragma unroll
    for (int i = 0; i < 8; i++) {
      int c = c0 + i8 * 8 + i;
      ov[i] = f2bf((vv[i8 * 8 + i] - mu) * rs * lng[c] + lnb[c]);
    }
    *(u16x8*)(out + gr * Dd + c0 + i8 * 8) = ov;
  }
}

// ---------------- edge gather: 16 edges/block, 16 lanes x u16x8 ----------------
__global__ __launch_bounds__(256) void k_gather_e(const unsigned short* __restrict__ X,
                                                  const int* __restrict__ seq,
                                                  unsigned short* __restrict__ EDGE) {
  int r = blockIdx.x * 16 + (threadIdx.x >> 4);
  int c0 = (threadIdx.x & 15) * 8;
  const int* row = seq + (size_t)r * Ll;
  float acc[8];
#pragma unroll
  for (int i = 0; i < 8; i++) acc[i] = 0.f;
  int cnt = 0;
#pragma unroll 1
  for (int l0 = 0; l0 < Ll; l0 += 10) {
    int ids[10];
#pragma unroll
    for (int t = 0; t < 10; t++) ids[t] = row[l0 + t];
    u16x8 vv[10];
#pragma unroll
    for (int t = 0; t < 10; t++)
      vv[t] = *(const u16x8*)(X + (size_t)ids[t] * Dd + c0);
#pragma unroll
    for (int t = 0; t < 10; t++)
      if (ids[t] > 0) {
        cnt++;
#pragma unroll
        for (int i = 0; i < 8; i++) acc[i] += bf2f(vv[t][i]);
      }
  }
  u16x8 ov;
  if (cnt) {
    float inv = 1.f / (float)cnt;
#pragma unroll
    for (int i = 0; i < 8; i++) ov[i] = f2bf(fmaxf(acc[i] * inv, 0.f));
  } else {
    u16x8 x0 = *(const u16x8*)(X + c0);
#pragma unroll
    for (int i = 0; i < 8; i++) ov[i] = f2bf(fmaxf(bf2f(x0[i]), 0.f));
  }
  *(u16x8*)(EDGE + (size_t)r * Dd + c0) = ov;
}

// ---------------- fused node-gather + hidden build (bf16 out only) ----------------
__global__ __launch_bounds__(256) void k_hidfuse(
    const unsigned short* __restrict__ E1, const int* __restrict__ data_idx,
    const int* __restrict__ seq, const int* __restrict__ tsmp,
    const int* __restrict__ uinf, const int* __restrict__ ulev,
    const int* __restrict__ useq,
    const float* __restrict__ time_emb, const float* __restrict__ inf_emb,
    const float* __restrict__ pos_emb,
    unsigned short* __restrict__ hidTb, unsigned short* __restrict__ hidSb) {
  int bl = blockIdx.x * 16 + (threadIdx.x >> 4);
  int c0 = (threadIdx.x & 15) * 8;
  int b = bl / Ll, l = bl % Ll;
  int e = data_idx[b];
  int sid = seq[(size_t)e * Ll + l];
  const int* urow = useq + (size_t)sid * LuU;
  float acc[8];
#pragma unroll
  for (int i = 0; i < 8; i++) acc[i] = 0.f;
  int cnt = 0;
#pragma unroll 1
  for (int t0 = 0; t0 < LuU; t0 += 10) {
    int ids[10];
#pragma unroll
    for (int t = 0; t < 10; t++) ids[t] = urow[t0 + t];
    u16x8 vv[10];
#pragma unroll
    for (int t = 0; t < 10; t++)
      vv[t] = *(const u16x8*)(E1 + (size_t)ids[t] * Dd + c0);
#pragma unroll
    for (int t = 0; t < 10; t++)
      if (ids[t] > 0) {
        cnt++;
#pragma unroll
        for (int i = 0; i < 8; i++) acc[i] += bf2f(vv[t][i]);
      }
  }
  float node[8];
  if (cnt) {
    float inv = 1.f / (float)cnt;
#pragma unroll
    for (int i = 0; i < 8; i++) node[i] = acc[i] * inv;
  } else {
    u16x8 e0 = *(const u16x8*)(E1 + c0);
#pragma unroll
    for (int i = 0; i < 8; i++) node[i] = bf2f(e0[i]);
  }
  int ts = tsmp[(size_t)e * Ll + l];
  int fi = uinf[(size_t)e * Ll + l];
  int lv = ulev[(size_t)e * Ll + l];
  const float4* tp = (const float4*)(time_emb + (size_t)ts * Dd + c0);
  const float4* ip = (const float4*)(inf_emb + (size_t)fi * Dd + c0);
  const float4* pp = (const float4*)(pos_emb + (size_t)lv * Dd + c0);
  float4 t0 = tp[0], t1 = tp[1];
  float4 i0 = ip[0], i1 = ip[1];
  float4 p0 = pp[0], p1 = pp[1];
  float te[8] = {t0.x, t0.y, t0.z, t0.w, t1.x, t1.y, t1.z, t1.w};
  float ie[8] = {i0.x, i0.y, i0.z, i0.w, i1.x, i1.y, i1.z, i1.w};
  float pe[8] = {p0.x, p0.y, p0.z, p0.w, p1.x, p1.y, p1.z, p1.w};
  u16x8 ht, hs;
#pragma unroll
  for (int i = 0; i < 8; i++) {
    ht[i] = f2bf(node[i] + te[i]);
    hs[i] = f2bf(node[i] + ie[i] + pe[i]);
  }
  size_t o = (size_t)bl * Dd + c0;
  *(u16x8*)(hidTb + o) = ht;
  *(u16x8*)(hidSb + o) = hs;
}

// ---------------- per-(branch,b,h) attention ----------------
__global__ __launch_bounds__(64) void k_attn(const unsigned short* __restrict__ qall,
                                             const unsigned short* __restrict__ kall,
                                             const unsigned short* __restrict__ vall,
                                             const int* __restrict__ data_idx,
                                             const int* __restrict__ seq,
                                             unsigned short* __restrict__ ctxall) {
  int branch = blockIdx.x >> 12;
  int b = (blockIdx.x >> 3) & 511;
  int h = blockIdx.x & 7;
  size_t boff = (size_t)branch * BL * Dd;
  const unsigned short* q = qall + boff;
  const unsigned short* k = kall + boff;
  const unsigned short* v = vall + boff;
  unsigned short* ctx = ctxall + boff;
  __shared__ float Kl[Ll][16], Vl[Ll][16];
  __shared__ int maskl[Ll];
  int e = data_idx[b];
  for (int i = threadIdx.x; i < Ll; i += 64)
    maskl[i] = (seq[(size_t)e * Ll + i] == 0);
  size_t base = (size_t)b * Ll * Dd + h * 16;
  for (int i = threadIdx.x; i < Ll * 16; i += 64) {
    int l = i >> 4, d = i & 15;
    size_t o = base + (size_t)l * Dd + d;
    Kl[l][d] = bf2f(k[o]);
    Vl[l][d] = bf2f(v[o]);
  }
  __syncthreads();
  int qi = threadIdx.x;
  if (qi < Ll) {
    size_t qo = base + (size_t)qi * Dd;
    const u16x8* qp = (const u16x8*)(q + qo);
    u16x8 q0 = qp[0], q1 = qp[1];
    float qv[16];
#pragma unroll
    for (int d = 0; d < 8; d++) { qv[d] = bf2f(q0[d]); qv[8 + d] = bf2f(q1[d]); }
    float sc[Ll];
    float m = -1e30f;
#pragma unroll
    for (int ki = 0; ki < Ll; ki++) {
      float s;
      if (maskl[ki]) s = -1e9f;
      else {
        s = 0.f;
#pragma unroll
        for (int d = 0; d < 16; d++) s += qv[d] * Kl[ki][d];
        s *= 0.25f;
      }
      sc[ki] = s;
      m = fmaxf(m, s);
    }
    float sum = 0.f;
#pragma unroll
    for (int ki = 0; ki < Ll; ki++) { float p = expf(sc[ki] - m); sc[ki] = p; sum += p; }
    float inv = 1.f / sum;
    float o[16];
#pragma unroll
    for (int d = 0; d < 16; d++) o[d] = 0.f;
#pragma unroll
    for (int ki = 0; ki < Ll; ki++) {
      float p = sc[ki];
#pragma unroll
      for (int d = 0; d < 16; d++) o[d] += p * Vl[ki][d];
    }
    unsigned* cp = (unsigned*)(ctx + qo);
#pragma unroll
    for (int d2 = 0; d2 < 8; d2++) {
      unsigned lo = f2bf(o[2 * d2] * inv), hi = f2bf(o[2 * d2 + 1] * inv);
      cp[d2] = lo | (hi << 16);
    }
  }
}

// ---------------- news weighted reduce (both branches): news[br][b][0..129] ----
__global__ __launch_bounds__(128) void k_newsred(const unsigned short* __restrict__ attall,
                                                 const int* __restrict__ data_idx,
                                                 const int* __restrict__ seq,
                                                 const float* __restrict__ spread,
                                                 float* __restrict__ news) {
  __shared__ int sl[Ll];
  __shared__ int scnt;
  int b = blockIdx.x, branch = blockIdx.y;
  int e = data_idx[b];
  const unsigned short* att = attall + (size_t)branch * BL * Dd;
  if (threadIdx.x < Ll) sl[threadIdx.x] = seq[(size_t)e * Ll + threadIdx.x];
  __syncthreads();
  if (threadIdx.x == 0) {
    int c = 0;
    for (int l = 0; l < Ll; l++) c += (sl[l] > 0);
    scnt = c;
  }
  __syncthreads();
  int cnt = scnt;
  float wnp = cnt ? 1.f / (float)cnt : 0.02f;   // weight for nonpad (or uniform)
  int c = threadIdx.x;
  float acc = 0.f;
  for (int l = 0; l < Ll; l++) {
    float w = cnt ? ((sl[l] > 0) ? wnp : 0.f) : wnp;
    acc += w * bf2f(att[((size_t)b * Ll + l) * Dd + c]);
  }
  float* nrow = news + ((size_t)branch * Bb + b) * 132;
  nrow[c] = acc;
  if (c < 2) {
    nrow[Dd + c] = branch ? spread[(size_t)e * 4 + c]
                          : spread[(size_t)e * 4 + 2 + c] * (1.f / 86400.f);
  }
}

// ---------------- news @ W (batched, W staged in LDS) ----------------
__global__ __launch_bounds__(256) void k_newsW(const float* __restrict__ news,
                                               const float* __restrict__ Wm,
                                               const float* __restrict__ W2m,
                                               float* __restrict__ NT,
                                               float* __restrict__ NS) {
  __shared__ float Wl[Dw][Dw + 1];
  __shared__ float nrow[132];
  int branch = blockIdx.y;
  const float* W = branch ? W2m : Wm;
  float* out = branch ? NS : NT;
  for (int u = threadIdx.x; u < Dw * Dw; u += 256)
    Wl[u / Dw][u % Dw] = W[u];
  for (int rr = 0; rr < 32; rr++) {
    int b = blockIdx.x * 32 + rr;
    __syncthreads();
    if (threadIdx.x < Dw)
      nrow[threadIdx.x] = news[((size_t)branch * Bb + b) * 132 + threadIdx.x];
    __syncthreads();
    int j = threadIdx.x;
    if (j < Dw) {
      float acc = 0.f;
      for (int kk = 0; kk < Dw; kk++) acc += nrow[kk] * Wl[kk][j];
      out[(size_t)b * Dw + j] = acc;
    }
  }
}

// ---------------- gated fusion + classifier + log_softmax ----------------
__global__ __launch_bounds__(256) void k_fusion(const float* __restrict__ nt,
                                                const float* __restrict__ ns,
                                                const float* __restrict__ l1w,
                                                const float* __restrict__ l1b,
                                                const float* __restrict__ l2w,
                                                const float* __restrict__ l2b,
                                                const float* __restrict__ linw,
                                                const float* __restrict__ linb,
                                                float* __restrict__ out) {
  __shared__ float rt[Dw], rs[Dw];
  __shared__ float scr[4];
  int b = blockIdx.x, j = threadIdx.x;
  if (j < Dw) { rt[j] = nt[(size_t)b * Dw + j]; rs[j] = ns[(size_t)b * Dw + j]; }
  __syncthreads();
  float pt = 0.f, ps = 0.f;
  if (j < Dw) {
    float at = l1b[j], as = l1b[j];
    for (int kk = 0; kk < Dw; kk++) {
      float w = l1w[(size_t)kk * Dw + j];
      at += rt[kk] * w;
      as += rs[kk] * w;
    }
    float lw2 = l2w[j];
    pt = tanhf(at) * lw2;
    ps = tanhf(as) * lw2;
  }
  float st = block_sum_256(pt, scr);
  float ss = block_sum_256(ps, scr);
  st += l2b[0]; ss += l2b[0];
  float m = fmaxf(st, ss);
  float e0 = expf(st - m), e1v = expf(ss - m);
  float inv = 1.f / (e0 + e1v);
  float s0 = e0 * inv, s1 = e1v * inv;
  float fj  = (j < Dw) ? (s0 * rt[j] + s1 * rs[j]) : 0.f;
  float w0  = (j < Dw) ? linw[(size_t)j * 2 + 0] : 0.f;
  float w1v = (j < Dw) ? linw[(size_t)j * 2 + 1] : 0.f;
  float l0 = block_sum_256(fj * w0, scr);
  float l1 = block_sum_256(fj * w1v, scr);
  if (j == 0) {
    l0 += linb[0]; l1 += linb[1];
    float mm = fmaxf(l0, l1);
    float lse = mm + logf(expf(l0 - mm) + expf(l1 - mm));
    out[(size_t)b * 2 + 0] = l0 - lse;
    out[(size_t)b * 2 + 1] = l1 - lse;
  }
}

extern "C" void kernel_launch(void* const* d_in, const int* in_sizes, int n_in,
                              void* d_out, int out_size, void* d_ws, size_t ws_size,
                              hipStream_t stream) {
  const int*   data_idx = (const int*)d_in[0];
  const int*   seq      = (const int*)d_in[1];
  const int*   tsmp     = (const int*)d_in[2];
  const int*   ulev     = (const int*)d_in[3];
  const int*   useq     = (const int*)d_in[4];
  const int*   uinf     = (const int*)d_in[5];
  const int*   ucen     = (const int*)d_in[6];
  const float* spread   = (const float*)d_in[7];
  const float* user_emb = (const float*)d_in[9];
  const float* cen_emb  = (const float*)d_in[10];
  const float* time_emb = (const float*)d_in[11];
  const float* pos_emb  = (const float*)d_in[12];
  const float* inf_emb  = (const float*)d_in[13];
  const float* w1       = (const float*)d_in[14];
  const float* w2       = (const float*)d_in[15];
  const float* w3       = (const float*)d_in[16];
  const float* Wm       = (const float*)d_in[17];
  const float* W2m      = (const float*)d_in[18];
  const float* f_l1_w   = (const float*)d_in[19];
  const float* f_l1_b   = (const float*)d_in[20];
  const float* f_l2_w   = (const float*)d_in[21];
  const float* f_l2_b   = (const float*)d_in[22];
  const float* lin_w    = (const float*)d_in[23];
  const float* lin_b    = (const float*)d_in[24];
  const float* t_wq = (const float*)d_in[25];
  const float* t_wk = (const float*)d_in[26];
  const float* t_wv = (const float*)d_in[27];
  const float* t_wo = (const float*)d_in[28];
  const float* t_g  = (const float*)d_in[29];
  const float* t_b  = (const float*)d_in[30];
  const float* s_wq = (const float*)d_in[31];
  const float* s_wk = (const float*)d_in[32];
  const float* s_wv = (const float*)d_in[33];
  const float* s_wo = (const float*)d_in[34];
  const float* s_g  = (const float*)d_in[35];
  const float* s_b  = (const float*)d_in[36];

  char* ws = (char*)d_ws;
  constexpr size_t SZ_WT  = (size_t)10 * Dd * Dd * 2;
  constexpr size_t SZ_XB  = (size_t)Nn * Dd * 2;
  constexpr size_t SZ_EB  = (size_t)Ee * Dd * 2;
  constexpr size_t SZ_BH  = (size_t)BL * Dd * 2;
  constexpr size_t OFF_WT  = 8192;
  constexpr size_t OFF_X   = OFF_WT + SZ_WT;
  constexpr size_t OFF_EDGE= OFF_X + SZ_XB;
  constexpr size_t OFF_E1  = OFF_EDGE + SZ_EB;
  constexpr size_t OFF_HTB = OFF_E1 + SZ_EB;
  constexpr size_t OFF_HSB = OFF_HTB + SZ_BH;
  constexpr size_t OFF_Q   = OFF_HSB + SZ_BH;       // 2 branches each
  constexpr size_t OFF_K   = OFF_Q + 2 * SZ_BH;
  constexpr size_t OFF_V   = OFF_K + 2 * SZ_BH;
  constexpr size_t OFF_CTX = OFF_V + 2 * SZ_BH;
  constexpr size_t OFF_ATT = OFF_CTX + 2 * SZ_BH;
  constexpr size_t OFF_NEWS= OFF_ATT + 2 * SZ_BH;
  constexpr size_t OFF_NT  = OFF_NEWS + (size_t)2 * Bb * 132 * 4;
  constexpr size_t OFF_NS  = OFF_NT + (size_t)Bb * Dw * 4;

  float* dotb    = (float*)(ws + 0);
  float* nrmb    = (float*)(ws + 3072);
  float* internw = (float*)(ws + 6144);
  unsigned short* WTall = (unsigned short*)(ws + OFF_WT);
  unsigned short* Xb    = (unsigned short*)(ws + OFF_X);
  unsigned short* EDGEb = (unsigned short*)(ws + OFF_EDGE);
  unsigned short* E1b   = (unsigned short*)(ws + OFF_E1);
  unsigned short* HIDTb = (unsigned short*)(ws + OFF_HTB);
  unsigned short* HIDSb = (unsigned short*)(ws + OFF_HSB);
  unsigned short* Qall  = (unsigned short*)(ws + OFF_Q);
  unsigned short* Kall  = (unsigned short*)(ws + OFF_K);
  unsigned short* Vall  = (unsigned short*)(ws + OFF_V);
  unsigned short* CTXall= (unsigned short*)(ws + OFF_CTX);
  unsigned short* ATTall= (unsigned short*)(ws + OFF_ATT);
  float*          NEWS  = (float*)(ws + OFF_NEWS);
  float*          NT    = (float*)(ws + OFF_NT);
  float*          NS    = (float*)(ws + OFF_NS);
  float* outp = (float*)d_out;

  // ---- prep ----
  k_prep<<<80, 256, 0, stream>>>(w1, w2, t_wq, t_wk, t_wv, t_wo,
                                 s_wq, s_wk, s_wv, s_wo, WTall);
  k_cos<<<TVv, 256, 0, stream>>>(w3, dotb, nrmb);
  k_internw<<<1, 256, 0, stream>>>(dotb, nrmb, internw);

  // ---- HGNN ----
  k_gemm_plain<0><<<(Nn + 63) / 64, 256, 0, stream>>>(
      user_emb, cen_emb, ucen, internw, WTall,
      nullptr, nullptr, nullptr, nullptr, nullptr, Xb, Nn);
  k_gather_e<<<Ee / 16, 256, 0, stream>>>(Xb, seq, EDGEb);
  k_gemm_plain<1><<<(Ee + 63) / 64, 256, 0, stream>>>(
      EDGEb, nullptr, nullptr, nullptr, WTall,
      nullptr, nullptr, nullptr, nullptr, nullptr, E1b, Ee);
  k_hidfuse<<<BL / 16, 256, 0, stream>>>(E1b, data_idx, seq, tsmp, uinf, ulev, useq,
                                         time_emb, inf_emb, pos_emb, HIDTb, HIDSb);

  // ---- QKV (both branches), attention, proj+LN ----
  k_gemm_plain<2><<<400 * 6, 256, 0, stream>>>(
      nullptr, nullptr, nullptr, nullptr, WTall,
      HIDTb, HIDSb, Qall, Kall, Vall, nullptr, BL);
  k_attn<<<2 * Bb * 8, 64, 0, stream>>>(Qall, Kall, Vall, data_idx, seq, CTXall);
  k_gemm_ln<<<400 * 2, 256, 0, stream>>>(CTXall, HIDTb, HIDSb, WTall,
                                         t_g, t_b, s_g, s_b, ATTall);

  // ---- news + fusion ----
  k_newsred<<<dim3(Bb, 2), 128, 0, stream>>>(ATTall, data_idx, seq, spread, NEWS);
  k_newsW<<<dim3(16, 2), 256, 0, stream>>>(NEWS, Wm, W2m, NT, NS);
  k_fusion<<<Bb, 256, 0, stream>>>(NT, NS, f_l1_w, f_l1_b, f_l2_w, f_l2_b,
                                   lin_w, lin_b, outp);

  (void)in_sizes; (void)n_in; (void)out_size; (void)ws_size;
}

// Round 4
// 357.856 us; speedup vs baseline: 2.2124x; 1.0316x over previous
//
#include <hip/hip_runtime.h>
#include <math.h>

constexpr int Nn = 50000;
constexpr int Ee = 10000;
constexpr int Ll = 50;
constexpr int LuU = 20;
constexpr int Dd = 128;
constexpr int Bb = 512;
constexpr int TVv = 768;
constexpr int Dw = 130;
constexpr int BL = Bb * Ll;   // 25600

typedef __attribute__((ext_vector_type(8))) short bf8v;
typedef __attribute__((ext_vector_type(4))) float f4v;
typedef __attribute__((ext_vector_type(8))) unsigned short u16x8;
typedef __attribute__((ext_vector_type(4))) unsigned short u16x4;

__device__ __forceinline__ unsigned short f2bf(float f) {
  union { float f; unsigned u; } v; v.f = f;
  unsigned r = v.u + 0x7FFFu + ((v.u >> 16) & 1u);
  return (unsigned short)(r >> 16);
}
__device__ __forceinline__ float bf2f(unsigned short h) {
  union { unsigned u; float f; } v; v.u = ((unsigned)h) << 16; return v.f;
}
// XOR swizzle for [rows][256B] tiles (16B slot by row&7)
__device__ __forceinline__ int swz(int b) { return b ^ (((b >> 8) & 7) << 4); }
// XOR swizzle for [rows][128B] tiles (16B slot by row&3, preserves 8B writes)
__device__ __forceinline__ int swzp(int b) { return b ^ (((b >> 7) & 3) << 4); }

// ---------------- block reduction ----------------
__device__ __forceinline__ float block_sum_256(float v, volatile float* scr) {
#pragma unroll
  for (int o = 32; o > 0; o >>= 1) v += __shfl_down(v, o, 64);
  __syncthreads();
  if ((threadIdx.x & 63) == 0) scr[threadIdx.x >> 6] = v;
  __syncthreads();
  return scr[0] + scr[1] + scr[2] + scr[3];
}

// ---------------- cosine / inter_nw ----------------
__global__ __launch_bounds__(256) void k_cos(const float* __restrict__ w3,
                                             float* __restrict__ dotb,
                                             float* __restrict__ nrmb) {
  __shared__ float scr[4];
  int i = blockIdx.x;
  const float* row = w3 + (size_t)i * TVv;
  float d = 0.f, n = 0.f;
  for (int j = threadIdx.x; j < TVv; j += 256) {
    float a = row[j];
    d += a * w3[j];
    n += a * a;
  }
  d = block_sum_256(d, scr);
  n = block_sum_256(n, scr);
  if (threadIdx.x == 0) { dotb[i] = d; nrmb[i] = n; }
}

__global__ __launch_bounds__(256) void k_internw(const float* __restrict__ dotb,
                                                 const float* __restrict__ nrmb,
                                                 float* __restrict__ internw) {
  __shared__ float scr[4];
  float n0 = sqrtf(nrmb[0]);
  float s = 0.f;
  for (int i = threadIdx.x; i < TVv; i += 256)
    s += dotb[i] / (n0 * sqrtf(nrmb[i]));
  s = block_sum_256(s, scr);
  if (threadIdx.x == 0) *internw = s / (float)TVv;
}

// ---------------- weight prep: f32 [k][n] -> bf16 [n][k] ----------------
__global__ __launch_bounds__(256) void k_prep(
    const float* w1, const float* w2,
    const float* twq, const float* twk, const float* twv, const float* two,
    const float* swq, const float* swk, const float* swv, const float* swo,
    unsigned short* __restrict__ out) {
  int wsel = blockIdx.x >> 3, part = blockIdx.x & 7;
  const float* w;
  switch (wsel) {
    case 0: w = w1; break;  case 1: w = w2; break;
    case 2: w = twq; break; case 3: w = twk; break;
    case 4: w = twv; break; case 5: w = two; break;
    case 6: w = swq; break; case 7: w = swk; break;
    case 8: w = swv; break; default: w = swo; break;
  }
  int u = part * 256 + threadIdx.x;
  int n = u >> 4, k0 = (u & 15) * 8;
  u16x8 pv;
#pragma unroll
  for (int i = 0; i < 8; i++) pv[i] = f2bf(w[(size_t)(k0 + i) * Dd + n]);
  ((u16x8*)(out + (size_t)wsel * Dd * Dd))[u] = pv;
}

// ---------------- MFMA GEMM (64-row tile, bf16 out) ----------------
// MODE 0: in=(user_emb+cen_emb[gidx])*scale (f32)   MODE 1: in=bf16
template <int MODE>
__global__ __launch_bounds__(256) void k_gemm_plain(
    const void* __restrict__ inA, const float* __restrict__ in1,
    const int* __restrict__ gidx, const float* __restrict__ scalep,
    const unsigned short* __restrict__ WTg,
    unsigned short* __restrict__ out, int nrows) {
  __shared__ unsigned short WT[Dd * Dd];
  __shared__ __align__(16) unsigned short Ab[64 * Dd];
  int tid = threadIdx.x;
  {
    const u16x8* src = (const u16x8*)WTg;
    for (int u = tid; u < 2048; u += 256)
      *(u16x8*)((char*)WT + swz(u * 16)) = src[u];
  }
  int r0 = blockIdx.x * 64;
  if constexpr (MODE == 0) {
    float sc = *scalep;
    for (int u = tid; u < 1024; u += 256) {
      int rr = u >> 4, c0 = (u & 15) * 8;
      int r = r0 + rr;
      u16x8 pv;
      if (r < nrows) {
        const float* a = (const float*)inA + (size_t)r * Dd + c0;
        const float* c = in1 + (size_t)gidx[r] * Dd + c0;
#pragma unroll
        for (int i = 0; i < 8; i++) pv[i] = f2bf((a[i] + c[i]) * sc);
      } else {
#pragma unroll
        for (int i = 0; i < 8; i++) pv[i] = 0;
      }
      *(u16x8*)((char*)Ab + swz(rr * 256 + c0 * 2)) = pv;
    }
  } else {
    for (int u = tid; u < 1024; u += 256) {
      int rr = u >> 4;
      int r = r0 + rr;
      u16x8 pv;
      if (r < nrows) pv = ((const u16x8*)inA)[(size_t)r * 16 + (u & 15)];
      else {
#pragma unroll
        for (int i = 0; i < 8; i++) pv[i] = 0;
      }
      *(u16x8*)((char*)Ab + swz(rr * 256 + (u & 15) * 16)) = pv;
    }
  }
  __syncthreads();
  int lane = tid & 63, wid = tid >> 6;
  int lrow = lane & 15, lg = lane >> 4;
  bf8v af[4];
#pragma unroll
  for (int kc = 0; kc < 4; kc++)
    af[kc] = *(const bf8v*)((char*)Ab + swz((wid * 16 + lrow) * 256 + kc * 64 + lg * 16));
  f4v acc[8];
#pragma unroll
  for (int nt = 0; nt < 8; nt++)
#pragma unroll
    for (int j = 0; j < 4; j++) acc[nt][j] = 0.f;
#pragma unroll
  for (int nt = 0; nt < 8; nt++)
#pragma unroll
    for (int kc = 0; kc < 4; kc++) {
      bf8v bfg = *(const bf8v*)((char*)WT + swz((nt * 16 + lrow) * 256 + kc * 64 + lg * 16));
      acc[nt] = __builtin_amdgcn_mfma_f32_16x16x32_bf16(af[kc], bfg, acc[nt], 0, 0, 0);
    }
#pragma unroll
  for (int nt = 0; nt < 8; nt++)
#pragma unroll
    for (int j = 0; j < 4; j++) {
      int r = r0 + wid * 16 + lg * 4 + j;
      if (r < nrows) out[(size_t)r * Dd + nt * 16 + lrow] = f2bf(acc[nt][j]);
    }
}

// ---------------- QKV GEMM: 128-row tile, A-frags in regs, 3 weights looped ----
__global__ __launch_bounds__(256) void k_gemm_qkv(
    const unsigned short* __restrict__ hidT, const unsigned short* __restrict__ hidS,
    const unsigned short* __restrict__ WTbase,
    unsigned short* __restrict__ outQ, unsigned short* __restrict__ outK,
    unsigned short* __restrict__ outV) {
  __shared__ unsigned short WT[Dd * Dd];          // 32 KB
  __shared__ __align__(16) unsigned short Ab[128 * Dd];  // 32 KB
  int tile = blockIdx.x % 200, branch = blockIdx.x / 200;
  const unsigned short* in = branch ? hidS : hidT;
  int r0 = tile * 128;
  int tid = threadIdx.x;
  for (int u = tid; u < 2048; u += 256) {
    int rr = u >> 4, ch = u & 15;
    u16x8 pv = ((const u16x8*)in)[(size_t)(r0 + rr) * 16 + ch];
    *(u16x8*)((char*)Ab + swz(rr * 256 + ch * 16)) = pv;
  }
  {
    const u16x8* srcW = (const u16x8*)(WTbase + (size_t)(2 + branch * 4) * Dd * Dd);
    for (int u = tid; u < 2048; u += 256)
      *(u16x8*)((char*)WT + swz(u * 16)) = srcW[u];
  }
  __syncthreads();
  int lane = tid & 63, wid = tid >> 6;
  int lrow = lane & 15, lg = lane >> 4;
  bf8v af[2][4];
#pragma unroll
  for (int mi = 0; mi < 2; mi++)
#pragma unroll
    for (int kc = 0; kc < 4; kc++)
      af[mi][kc] = *(const bf8v*)((char*)Ab +
                    swz((wid * 32 + mi * 16 + lrow) * 256 + kc * 64 + lg * 16));
#pragma unroll 1
  for (int sel = 0; sel < 3; sel++) {
    f4v acc[2][8];
#pragma unroll
    for (int mi = 0; mi < 2; mi++)
#pragma unroll
      for (int nt = 0; nt < 8; nt++)
#pragma unroll
        for (int j = 0; j < 4; j++) acc[mi][nt][j] = 0.f;
#pragma unroll
    for (int nt = 0; nt < 8; nt++)
#pragma unroll
      for (int kc = 0; kc < 4; kc++) {
        bf8v bfg = *(const bf8v*)((char*)WT + swz((nt * 16 + lrow) * 256 + kc * 64 + lg * 16));
        acc[0][nt] = __builtin_amdgcn_mfma_f32_16x16x32_bf16(af[0][kc], bfg, acc[0][nt], 0, 0, 0);
        acc[1][nt] = __builtin_amdgcn_mfma_f32_16x16x32_bf16(af[1][kc], bfg, acc[1][nt], 0, 0, 0);
      }
    unsigned short* outb = ((sel == 0) ? outQ : (sel == 1) ? outK : outV)
                           + (size_t)branch * BL * Dd;
#pragma unroll
    for (int mi = 0; mi < 2; mi++)
#pragma unroll
      for (int nt = 0; nt < 8; nt++)
#pragma unroll
        for (int j = 0; j < 4; j++) {
          int r = r0 + wid * 32 + mi * 16 + lg * 4 + j;
          outb[(size_t)r * Dd + nt * 16 + lrow] = f2bf(acc[mi][nt][j]);
        }
    if (sel < 2) {
      __syncthreads();
      const u16x8* srcW = (const u16x8*)(WTbase + (size_t)(2 + branch * 4 + sel + 1) * Dd * Dd);
      for (int u = tid; u < 2048; u += 256)
        *(u16x8*)((char*)WT + swz(u * 16)) = srcW[u];
      __syncthreads();
    }
  }
}

// ---------------- MFMA GEMM + residual + LayerNorm (both branches) ----------------
__global__ __launch_bounds__(256) void k_gemm_ln(
    const unsigned short* __restrict__ ctxall,
    const unsigned short* __restrict__ hidT, const unsigned short* __restrict__ hidS,
    const unsigned short* __restrict__ WTbase,
    const float* __restrict__ tg, const float* __restrict__ tb,
    const float* __restrict__ sg, const float* __restrict__ sb_,
    unsigned short* __restrict__ attall) {
  __shared__ unsigned short WT[Dd * Dd];
  __shared__ __align__(16) char UB[64 * 132 * 4];
  unsigned short* Ab = (unsigned short*)UB;
  float (*O)[132] = (float (*)[132])UB;

  int tile = blockIdx.x % 400, branch = blockIdx.x / 400;
  const unsigned short* in = ctxall + (size_t)branch * BL * Dd;
  const unsigned short* resid = (branch ? hidS : hidT);
  const unsigned short* Wg = WTbase + (size_t)(5 + branch * 4) * Dd * Dd;
  const float* lng = branch ? sg : tg;
  const float* lnb = branch ? sb_ : tb;
  unsigned short* out = attall + (size_t)branch * BL * Dd;
  int r0 = tile * 64;
  int tid = threadIdx.x;

  {
    const u16x8* src = (const u16x8*)Wg;
    for (int u = tid; u < 2048; u += 256)
      *(u16x8*)((char*)WT + swz(u * 16)) = src[u];
  }
  for (int u = tid; u < 1024; u += 256) {
    int rr = u >> 4;
    u16x8 pv = ((const u16x8*)in)[(size_t)(r0 + rr) * 16 + (u & 15)];
    *(u16x8*)((char*)Ab + swz(rr * 256 + (u & 15) * 16)) = pv;
  }
  __syncthreads();

  int lane = tid & 63, wid = tid >> 6;
  int lrow = lane & 15, lg = lane >> 4;
  bf8v af[4];
#pragma unroll
  for (int kc = 0; kc < 4; kc++)
    af[kc] = *(const bf8v*)((char*)Ab + swz((wid * 16 + lrow) * 256 + kc * 64 + lg * 16));
  f4v acc[8];
#pragma unroll
  for (int nt = 0; nt < 8; nt++)
#pragma unroll
    for (int j = 0; j < 4; j++) acc[nt][j] = 0.f;
#pragma unroll
  for (int nt = 0; nt < 8; nt++)
#pragma unroll
    for (int kc = 0; kc < 4; kc++) {
      bf8v bfg = *(const bf8v*)((char*)WT + swz((nt * 16 + lrow) * 256 + kc * 64 + lg * 16));
      acc[nt] = __builtin_amdgcn_mfma_f32_16x16x32_bf16(af[kc], bfg, acc[nt], 0, 0, 0);
    }
  __syncthreads();
#pragma unroll
  for (int nt = 0; nt < 8; nt++)
#pragma unroll
    for (int j = 0; j < 4; j++)
      O[wid * 16 + lg * 4 + j][nt * 16 + lrow] = acc[nt][j];
  __syncthreads();
  int r = tid >> 2, c0 = (tid & 3) * 32;
  size_t gr = (size_t)(r0 + r);
  float vv[32];
  float s1 = 0.f, s2 = 0.f;
#pragma unroll
  for (int i8 = 0; i8 < 4; i8++) {
    u16x8 hb = *(const u16x8*)(resid + gr * Dd + c0 + i8 * 8);
#pragma unroll
    for (int i = 0; i < 8; i++) {
      float x = O[r][c0 + i8 * 8 + i] + bf2f(hb[i]);
      vv[i8 * 8 + i] = x; s1 += x; s2 += x * x;
    }
  }
  s1 += __shfl_xor(s1, 1, 64); s2 += __shfl_xor(s2, 1, 64);
  s1 += __shfl_xor(s1, 2, 64); s2 += __shfl_xor(s2, 2, 64);
  float mu = s1 * (1.f / Dd);
  float var = s2 * (1.f / Dd) - mu * mu;
  float rs = rsqrtf(var + 1e-6f);
#pragma unroll
  for (int i8 = 0; i8 < 4; i8++) {
    u16x8 ov;
#pragma unroll
    for (int i = 0; i < 8; i++) {
      int c = c0 + i8 * 8 + i;
      ov[i] = f2bf((vv[i8 * 8 + i] - mu) * rs * lng[c] + lnb[c]);
    }
    *(u16x8*)(out + gr * Dd + c0 + i8 * 8) = ov;
  }
}

// ---------------- edge gather ----------------
__global__ __launch_bounds__(256) void k_gather_e(const unsigned short* __restrict__ X,
                                                  const int* __restrict__ seq,
                                                  unsigned short* __restrict__ EDGE) {
  int r = blockIdx.x * 16 + (threadIdx.x >> 4);
  int c0 = (threadIdx.x & 15) * 8;
  const int* row = seq + (size_t)r * Ll;
  float acc[8];
#pragma unroll
  for (int i = 0; i < 8; i++) acc[i] = 0.f;
  int cnt = 0;
#pragma unroll 1
  for (int l0 = 0; l0 < Ll; l0 += 10) {
    int ids[10];
#pragma unroll
    for (int t = 0; t < 10; t++) ids[t] = row[l0 + t];
    u16x8 vv[10];
#pragma unroll
    for (int t = 0; t < 10; t++)
      vv[t] = *(const u16x8*)(X + (size_t)ids[t] * Dd + c0);
#pragma unroll
    for (int t = 0; t < 10; t++)
      if (ids[t] > 0) {
        cnt++;
#pragma unroll
        for (int i = 0; i < 8; i++) acc[i] += bf2f(vv[t][i]);
      }
  }
  u16x8 ov;
  if (cnt) {
    float inv = 1.f / (float)cnt;
#pragma unroll
    for (int i = 0; i < 8; i++) ov[i] = f2bf(fmaxf(acc[i] * inv, 0.f));
  } else {
    u16x8 x0 = *(const u16x8*)(X + c0);
#pragma unroll
    for (int i = 0; i < 8; i++) ov[i] = f2bf(fmaxf(bf2f(x0[i]), 0.f));
  }
  *(u16x8*)(EDGE + (size_t)r * Dd + c0) = ov;
}

// ---------------- fused node-gather + hidden build ----------------
__global__ __launch_bounds__(256) void k_hidfuse(
    const unsigned short* __restrict__ E1, const int* __restrict__ data_idx,
    const int* __restrict__ seq, const int* __restrict__ tsmp,
    const int* __restrict__ uinf, const int* __restrict__ ulev,
    const int* __restrict__ useq,
    const float* __restrict__ time_emb, const float* __restrict__ inf_emb,
    const float* __restrict__ pos_emb,
    unsigned short* __restrict__ hidTb, unsigned short* __restrict__ hidSb) {
  int bl = blockIdx.x * 16 + (threadIdx.x >> 4);
  int c0 = (threadIdx.x & 15) * 8;
  int b = bl / Ll, l = bl % Ll;
  int e = data_idx[b];
  int sid = seq[(size_t)e * Ll + l];
  const int* urow = useq + (size_t)sid * LuU;
  float acc[8];
#pragma unroll
  for (int i = 0; i < 8; i++) acc[i] = 0.f;
  int cnt = 0;
#pragma unroll 1
  for (int t0 = 0; t0 < LuU; t0 += 10) {
    int ids[10];
#pragma unroll
    for (int t = 0; t < 10; t++) ids[t] = urow[t0 + t];
    u16x8 vv[10];
#pragma unroll
    for (int t = 0; t < 10; t++)
      vv[t] = *(const u16x8*)(E1 + (size_t)ids[t] * Dd + c0);
#pragma unroll
    for (int t = 0; t < 10; t++)
      if (ids[t] > 0) {
        cnt++;
#pragma unroll
        for (int i = 0; i < 8; i++) acc[i] += bf2f(vv[t][i]);
      }
  }
  float node[8];
  if (cnt) {
    float inv = 1.f / (float)cnt;
#pragma unroll
    for (int i = 0; i < 8; i++) node[i] = acc[i] * inv;
  } else {
    u16x8 e0 = *(const u16x8*)(E1 + c0);
#pragma unroll
    for (int i = 0; i < 8; i++) node[i] = bf2f(e0[i]);
  }
  int ts = tsmp[(size_t)e * Ll + l];
  int fi = uinf[(size_t)e * Ll + l];
  int lv = ulev[(size_t)e * Ll + l];
  const float4* tp = (const float4*)(time_emb + (size_t)ts * Dd + c0);
  const float4* ip = (const float4*)(inf_emb + (size_t)fi * Dd + c0);
  const float4* pp = (const float4*)(pos_emb + (size_t)lv * Dd + c0);
  float4 t0 = tp[0], t1 = tp[1];
  float4 i0 = ip[0], i1 = ip[1];
  float4 p0 = pp[0], p1 = pp[1];
  float te[8] = {t0.x, t0.y, t0.z, t0.w, t1.x, t1.y, t1.z, t1.w};
  float ie[8] = {i0.x, i0.y, i0.z, i0.w, i1.x, i1.y, i1.z, i1.w};
  float pe[8] = {p0.x, p0.y, p0.z, p0.w, p1.x, p1.y, p1.z, p1.w};
  u16x8 ht, hs;
#pragma unroll
  for (int i = 0; i < 8; i++) {
    ht[i] = f2bf(node[i] + te[i]);
    hs[i] = f2bf(node[i] + ie[i] + pe[i]);
  }
  size_t o = (size_t)bl * Dd + c0;
  *(u16x8*)(hidTb + o) = ht;
  *(u16x8*)(hidSb + o) = hs;
}

// ---------------- MFMA attention: one block per (branch, b) ----------------
// S^T = K_h @ Q_h^T via mfma (C layout: row=k, col=q); softmax over k per-lane
// + shfl; P^T -> LDS [q][k]; O^T = V_h^T @ P^T; write ctx[q][h*16+d].
__global__ __launch_bounds__(256) void k_attn_mfma(
    const unsigned short* __restrict__ qall,
    const unsigned short* __restrict__ kall,
    const unsigned short* __restrict__ vall,
    const int* __restrict__ data_idx,
    const int* __restrict__ seq,
    unsigned short* __restrict__ ctxall) {
  __shared__ __align__(16) unsigned short QKV[3 * 64 * 128];  // 48 KB swz'd
  __shared__ __align__(16) unsigned short PT[4 * 64 * 64];    // 32 KB, 8 KB/wave
  __shared__ int maskl[Ll];
  int b = blockIdx.x, branch = blockIdx.y;
  size_t boff = (size_t)branch * BL * Dd + (size_t)b * Ll * Dd;
  const unsigned short* qg = qall + boff;
  const unsigned short* kg = kall + boff;
  const unsigned short* vg = vall + boff;
  int tid = threadIdx.x;
  int e = data_idx[b];
  if (tid < Ll) maskl[tid] = (seq[(size_t)e * Ll + tid] == 0);
  for (int u = tid; u < 3072; u += 256) {
    int t = u >> 10, rem = u & 1023;
    int row = rem >> 4, ch = rem & 15;
    u16x8 pv;
    if (row < Ll) {
      const unsigned short* src = (t == 0) ? qg : (t == 1) ? kg : vg;
      pv = *(const u16x8*)(src + (size_t)row * Dd + ch * 8);
    } else {
#pragma unroll
      for (int i = 0; i < 8; i++) pv[i] = 0;
    }
    *(u16x8*)((char*)QKV + t * 16384 + swz(row * 256 + ch * 16)) = pv;
  }
  __syncthreads();
  int lane = tid & 63, wid = tid >> 6;
  int lrow = lane & 15, lg = lane >> 4;
  const char* Qb = (const char*)QKV;
  const char* Kb = (const char*)QKV + 16384;
  const char* Vb = (const char*)QKV + 32768;
  char* PTw = (char*)PT + wid * 8192;
  unsigned short* ctx = ctxall + boff;

#pragma unroll 1
  for (int hi = 0; hi < 2; hi++) {
    int h = wid * 2 + hi;
    int cb = h * 32;   // byte offset of head's 16 cols in a 256B row
    // ---- S^T = K_h @ Q_h^T ----
    bf8v af[4], bf[4];
    if (lg < 2) {
#pragma unroll
      for (int mt = 0; mt < 4; mt++)
        af[mt] = *(const bf8v*)(Kb + swz((mt * 16 + lrow) * 256 + cb + lg * 16));
#pragma unroll
      for (int nt = 0; nt < 4; nt++)
        bf[nt] = *(const bf8v*)(Qb + swz((nt * 16 + lrow) * 256 + cb + lg * 16));
    } else {
#pragma unroll
      for (int t = 0; t < 4; t++)
#pragma unroll
        for (int i = 0; i < 8; i++) { af[t][i] = 0; bf[t][i] = 0; }
    }
    f4v acc[16];
#pragma unroll
    for (int t = 0; t < 16; t++)
#pragma unroll
      for (int j = 0; j < 4; j++) acc[t][j] = 0.f;
#pragma unroll
    for (int mt = 0; mt < 4; mt++)
#pragma unroll
      for (int nt = 0; nt < 4; nt++)
        acc[mt * 4 + nt] =
            __builtin_amdgcn_mfma_f32_16x16x32_bf16(af[mt], bf[nt], acc[mt * 4 + nt], 0, 0, 0);
    // ---- scale + mask (in place) ----
#pragma unroll
    for (int mt = 0; mt < 4; mt++)
#pragma unroll
      for (int j = 0; j < 4; j++) {
        int kk = mt * 16 + lg * 4 + j;
        bool pad = (kk >= Ll);
        bool mk = !pad && (maskl[pad ? 0 : kk] != 0);
#pragma unroll
        for (int nt = 0; nt < 4; nt++) {
          float v = acc[mt * 4 + nt][j] * 0.25f;
          v = mk ? -1e9f : v;
          v = pad ? -3.0e38f : v;
          acc[mt * 4 + nt][j] = v;
        }
      }
    // ---- softmax over k per q-col + write P^T[q][k] ----
#pragma unroll
    for (int nt = 0; nt < 4; nt++) {
      float m = -3.0e38f;
#pragma unroll
      for (int mt = 0; mt < 4; mt++)
#pragma unroll
        for (int j = 0; j < 4; j++) m = fmaxf(m, acc[mt * 4 + nt][j]);
      m = fmaxf(m, __shfl_xor(m, 16, 64));
      m = fmaxf(m, __shfl_xor(m, 32, 64));
      float s = 0.f;
#pragma unroll
      for (int mt = 0; mt < 4; mt++)
#pragma unroll
        for (int j = 0; j < 4; j++) {
          float p = expf(acc[mt * 4 + nt][j] - m);
          acc[mt * 4 + nt][j] = p;
          s += p;
        }
      s += __shfl_xor(s, 16, 64);
      s += __shfl_xor(s, 32, 64);
      float inv = 1.f / s;
      int q = nt * 16 + lrow;
#pragma unroll
      for (int mt = 0; mt < 4; mt++) {
        u16x4 pw;
#pragma unroll
        for (int j = 0; j < 4; j++) pw[j] = f2bf(acc[mt * 4 + nt][j] * inv);
        *(u16x4*)(PTw + swzp(q * 128 + mt * 32 + lg * 8)) = pw;
      }
    }
    // ---- O^T = V_h^T @ P^T ----
    f4v pacc[4];
#pragma unroll
    for (int nt = 0; nt < 4; nt++)
#pragma unroll
      for (int j = 0; j < 4; j++) pacc[nt][j] = 0.f;
#pragma unroll
    for (int kt = 0; kt < 2; kt++) {
      bf8v av;
#pragma unroll
      for (int i = 0; i < 8; i++)
        av[i] = *(const short*)(Vb + swz((kt * 32 + lg * 8 + i) * 256 + cb + lrow * 2));
#pragma unroll
      for (int nt = 0; nt < 4; nt++) {
        bf8v bv = *(const bf8v*)(PTw + swzp((nt * 16 + lrow) * 128 + kt * 64 + lg * 16));
        pacc[nt] = __builtin_amdgcn_mfma_f32_16x16x32_bf16(av, bv, pacc[nt], 0, 0, 0);
      }
    }
#pragma unroll
    for (int nt = 0; nt < 4; nt++) {
      int q = nt * 16 + lrow;
      if (q < Ll) {
        u16x4 ow;
#pragma unroll
        for (int j = 0; j < 4; j++) ow[j] = f2bf(pacc[nt][j]);
        *(u16x4*)(ctx + (size_t)q * Dd + h * 16 + lg * 4) = ow;
      }
    }
  }
}

// ---------------- news weighted reduce ----------------
__global__ __launch_bounds__(128) void k_newsred(const unsigned short* __restrict__ attall,
                                                 const int* __restrict__ data_idx,
                                                 const int* __restrict__ seq,
                                                 const float* __restrict__ spread,
                                                 float* __restrict__ news) {
  __shared__ int sl[Ll];
  __shared__ int scnt;
  int b = blockIdx.x, branch = blockIdx.y;
  int e = data_idx[b];
  const unsigned short* att = attall + (size_t)branch * BL * Dd;
  if (threadIdx.x < Ll) sl[threadIdx.x] = seq[(size_t)e * Ll + threadIdx.x];
  __syncthreads();
  if (threadIdx.x == 0) {
    int c = 0;
    for (int l = 0; l < Ll; l++) c += (sl[l] > 0);
    scnt = c;
  }
  __syncthreads();
  int cnt = scnt;
  float wnp = cnt ? 1.f / (float)cnt : 0.02f;
  int c = threadIdx.x;
  float acc = 0.f;
  for (int l = 0; l < Ll; l++) {
    float w = cnt ? ((sl[l] > 0) ? wnp : 0.f) : wnp;
    acc += w * bf2f(att[((size_t)b * Ll + l) * Dd + c]);
  }
  float* nrow = news + ((size_t)branch * Bb + b) * 132;
  nrow[c] = acc;
  if (c < 2) {
    nrow[Dd + c] = branch ? spread[(size_t)e * 4 + c]
                          : spread[(size_t)e * 4 + 2 + c] * (1.f / 86400.f);
  }
}

// ---------------- news @ W ----------------
__global__ __launch_bounds__(256) void k_newsW(const float* __restrict__ news,
                                               const float* __restrict__ Wm,
                                               const float* __restrict__ W2m,
                                               float* __restrict__ NT,
                                               float* __restrict__ NS) {
  __shared__ float Wl[Dw][Dw + 1];
  __shared__ float nrow[132];
  int branch = blockIdx.y;
  const float* W = branch ? W2m : Wm;
  float* out = branch ? NS : NT;
  for (int u = threadIdx.x; u < Dw * Dw; u += 256)
    Wl[u / Dw][u % Dw] = W[u];
  for (int rr = 0; rr < 32; rr++) {
    int b = blockIdx.x * 32 + rr;
    __syncthreads();
    if (threadIdx.x < Dw)
      nrow[threadIdx.x] = news[((size_t)branch * Bb + b) * 132 + threadIdx.x];
    __syncthreads();
    int j = threadIdx.x;
    if (j < Dw) {
      float acc = 0.f;
      for (int kk = 0; kk < Dw; kk++) acc += nrow[kk] * Wl[kk][j];
      out[(size_t)b * Dw + j] = acc;
    }
  }
}

// ---------------- gated fusion + classifier + log_softmax ----------------
__global__ __launch_bounds__(256) void k_fusion(const float* __restrict__ nt,
                                                const float* __restrict__ ns,
                                                const float* __restrict__ l1w,
                                                const float* __restrict__ l1b,
                                                const float* __restrict__ l2w,
                                                const float* __restrict__ l2b,
                                                const float* __restrict__ linw,
                                                const float* __restrict__ linb,
                                                float* __restrict__ out) {
  __shared__ float rt[Dw], rs[Dw];
  __shared__ float scr[4];
  int b = blockIdx.x, j = threadIdx.x;
  if (j < Dw) { rt[j] = nt[(size_t)b * Dw + j]; rs[j] = ns[(size_t)b * Dw + j]; }
  __syncthreads();
  float pt = 0.f, ps = 0.f;
  if (j < Dw) {
    float at = l1b[j], as = l1b[j];
    for (int kk = 0; kk < Dw; kk++) {
      float w = l1w[(size_t)kk * Dw + j];
      at += rt[kk] * w;
      as += rs[kk] * w;
    }
    float lw2 = l2w[j];
    pt = tanhf(at) * lw2;
    ps = tanhf(as) * lw2;
  }
  float st = block_sum_256(pt, scr);
  float ss = block_sum_256(ps, scr);
  st += l2b[0]; ss += l2b[0];
  float m = fmaxf(st, ss);
  float e0 = expf(st - m), e1v = expf(ss - m);
  float inv = 1.f / (e0 + e1v);
  float s0 = e0 * inv, s1 = e1v * inv;
  float fj  = (j < Dw) ? (s0 * rt[j] + s1 * rs[j]) : 0.f;
  float w0  = (j < Dw) ? linw[(size_t)j * 2 + 0] : 0.f;
  float w1v = (j < Dw) ? linw[(size_t)j * 2 + 1] : 0.f;
  float l0 = block_sum_256(fj * w0, scr);
  float l1 = block_sum_256(fj * w1v, scr);
  if (j == 0) {
    l0 += linb[0]; l1 += linb[1];
    float mm = fmaxf(l0, l1);
    float lse = mm + logf(expf(l0 - mm) + expf(l1 - mm));
    out[(size_t)b * 2 + 0] = l0 - lse;
    out[(size_t)b * 2 + 1] = l1 - lse;
  }
}

extern "C" void kernel_launch(void* const* d_in, const int* in_sizes, int n_in,
                              void* d_out, int out_size, void* d_ws, size_t ws_size,
                              hipStream_t stream) {
  const int*   data_idx = (const int*)d_in[0];
  const int*   seq      = (const int*)d_in[1];
  const int*   tsmp     = (const int*)d_in[2];
  const int*   ulev     = (const int*)d_in[3];
  const int*   useq     = (const int*)d_in[4];
  const int*   uinf     = (const int*)d_in[5];
  const int*   ucen     = (const int*)d_in[6];
  const float* spread   = (const float*)d_in[7];
  const float* user_emb = (const float*)d_in[9];
  const float* cen_emb  = (const float*)d_in[10];
  const float* time_emb = (const float*)d_in[11];
  const float* pos_emb  = (const float*)d_in[12];
  const float* inf_emb  = (const float*)d_in[13];
  const float* w1       = (const float*)d_in[14];
  const float* w2       = (const float*)d_in[15];
  const float* w3       = (const float*)d_in[16];
  const float* Wm       = (const float*)d_in[17];
  const float* W2m      = (const float*)d_in[18];
  const float* f_l1_w   = (const float*)d_in[19];
  const float* f_l1_b   = (const float*)d_in[20];
  const float* f_l2_w   = (const float*)d_in[21];
  const float* f_l2_b   = (const float*)d_in[22];
  const float* lin_w    = (const float*)d_in[23];
  const float* lin_b    = (const float*)d_in[24];
  const float* t_wq = (const float*)d_in[25];
  const float* t_wk = (const float*)d_in[26];
  const float* t_wv = (const float*)d_in[27];
  const float* t_wo = (const float*)d_in[28];
  const float* t_g  = (const float*)d_in[29];
  const float* t_b  = (const float*)d_in[30];
  const float* s_wq = (const float*)d_in[31];
  const float* s_wk = (const float*)d_in[32];
  const float* s_wv = (const float*)d_in[33];
  const float* s_wo = (const float*)d_in[34];
  const float* s_g  = (const float*)d_in[35];
  const float* s_b  = (const float*)d_in[36];

  char* ws = (char*)d_ws;
  constexpr size_t SZ_WT  = (size_t)10 * Dd * Dd * 2;
  constexpr size_t SZ_XB  = (size_t)Nn * Dd * 2;
  constexpr size_t SZ_EB  = (size_t)Ee * Dd * 2;
  constexpr size_t SZ_BH  = (size_t)BL * Dd * 2;
  constexpr size_t OFF_WT  = 8192;
  constexpr size_t OFF_X   = OFF_WT + SZ_WT;
  constexpr size_t OFF_EDGE= OFF_X + SZ_XB;
  constexpr size_t OFF_E1  = OFF_EDGE + SZ_EB;
  constexpr size_t OFF_HTB = OFF_E1 + SZ_EB;
  constexpr size_t OFF_HSB = OFF_HTB + SZ_BH;
  constexpr size_t OFF_Q   = OFF_HSB + SZ_BH;
  constexpr size_t OFF_K   = OFF_Q + 2 * SZ_BH;
  constexpr size_t OFF_V   = OFF_K + 2 * SZ_BH;
  constexpr size_t OFF_CTX = OFF_V + 2 * SZ_BH;
  constexpr size_t OFF_ATT = OFF_CTX + 2 * SZ_BH;
  constexpr size_t OFF_NEWS= OFF_ATT + 2 * SZ_BH;
  constexpr size_t OFF_NT  = OFF_NEWS + (size_t)2 * Bb * 132 * 4;
  constexpr size_t OFF_NS  = OFF_NT + (size_t)Bb * Dw * 4;

  float* dotb    = (float*)(ws + 0);
  float* nrmb    = (float*)(ws + 3072);
  float* internw = (float*)(ws + 6144);
  unsigned short* WTall = (unsigned short*)(ws + OFF_WT);
  unsigned short* Xb    = (unsigned short*)(ws + OFF_X);
  unsigned short* EDGEb = (unsigned short*)(ws + OFF_EDGE);
  unsigned short* E1b   = (unsigned short*)(ws + OFF_E1);
  unsigned short* HIDTb = (unsigned short*)(ws + OFF_HTB);
  unsigned short* HIDSb = (unsigned short*)(ws + OFF_HSB);
  unsigned short* Qall  = (unsigned short*)(ws + OFF_Q);
  unsigned short* Kall  = (unsigned short*)(ws + OFF_K);
  unsigned short* Vall  = (unsigned short*)(ws + OFF_V);
  unsigned short* CTXall= (unsigned short*)(ws + OFF_CTX);
  unsigned short* ATTall= (unsigned short*)(ws + OFF_ATT);
  float*          NEWS  = (float*)(ws + OFF_NEWS);
  float*          NT    = (float*)(ws + OFF_NT);
  float*          NS    = (float*)(ws + OFF_NS);
  float* outp = (float*)d_out;

  k_prep<<<80, 256, 0, stream>>>(w1, w2, t_wq, t_wk, t_wv, t_wo,
                                 s_wq, s_wk, s_wv, s_wo, WTall);
  k_cos<<<TVv, 256, 0, stream>>>(w3, dotb, nrmb);
  k_internw<<<1, 256, 0, stream>>>(dotb, nrmb, internw);

  k_gemm_plain<0><<<(Nn + 63) / 64, 256, 0, stream>>>(
      user_emb, cen_emb, ucen, internw, WTall + 0 * Dd * Dd, Xb, Nn);
  k_gather_e<<<Ee / 16, 256, 0, stream>>>(Xb, seq, EDGEb);
  k_gemm_plain<1><<<(Ee + 63) / 64, 256, 0, stream>>>(
      EDGEb, nullptr, nullptr, nullptr, WTall + 1 * Dd * Dd, E1b, Ee);
  k_hidfuse<<<BL / 16, 256, 0, stream>>>(E1b, data_idx, seq, tsmp, uinf, ulev, useq,
                                         time_emb, inf_emb, pos_emb, HIDTb, HIDSb);

  k_gemm_qkv<<<400, 256, 0, stream>>>(HIDTb, HIDSb, WTall, Qall, Kall, Vall);
  k_attn_mfma<<<dim3(Bb, 2), 256, 0, stream>>>(Qall, Kall, Vall, data_idx, seq, CTXall);
  k_gemm_ln<<<400 * 2, 256, 0, stream>>>(CTXall, HIDTb, HIDSb, WTall,
                                         t_g, t_b, s_g, s_b, ATTall);

  k_newsred<<<dim3(Bb, 2), 128, 0, stream>>>(ATTall, data_idx, seq, spread, NEWS);
  k_newsW<<<dim3(16, 2), 256, 0, stream>>>(NEWS, Wm, W2m, NT, NS);
  k_fusion<<<Bb, 256, 0, stream>>>(NT, NS, f_l1_w, f_l1_b, f_l2_w, f_l2_b,
                                   lin_w, lin_b, outp);

  (void)in_sizes; (void)n_in; (void)out_size; (void)ws_size;
}